// Round 1
// baseline (4857.059 us; speedup 1.0000x reference)
//
#include <hip/hip_runtime.h>
#include <hip/hip_bf16.h>
#include <math.h>

#define F_    8
#define DIM_  1920
#define HEADS_ 30
#define HD_   64
#define RANK_ 128
#define T_    226
#define SV_   2048
#define S_    2274

// ---------------- generic tiled fp32 GEMM: C = A(MxK) @ B(NxK)^T + bias ----
// remap!=0: output row r -> (r>=T_ ? r-T_ : SV_+r)   (tuple return order)
__global__ __launch_bounds__(256) void gemm_nt(
    const float* __restrict__ A, const float* __restrict__ B,
    const float* __restrict__ bias, float* __restrict__ C,
    int M, int N, int K, int remap)
{
  __shared__ float As[16][68];
  __shared__ float Bs[16][68];
  const int tid = threadIdx.x;
  const int tx = tid & 15, ty = tid >> 4;
  const int row0 = blockIdx.y * 64, col0 = blockIdx.x * 64;
  const int lm = tid >> 2;           // 0..63
  const int lk = (tid & 3) << 2;     // 0,4,8,12
  float acc[4][4] = {};
  for (int k0 = 0; k0 < K; k0 += 16) {
    int ar = row0 + lm;
    float4 av = make_float4(0.f, 0.f, 0.f, 0.f);
    if (ar < M) av = *(const float4*)(A + (size_t)ar * K + k0 + lk);
    float4 bv = *(const float4*)(B + (size_t)(col0 + lm) * K + k0 + lk);
    __syncthreads();
    As[lk+0][lm] = av.x; As[lk+1][lm] = av.y; As[lk+2][lm] = av.z; As[lk+3][lm] = av.w;
    Bs[lk+0][lm] = bv.x; Bs[lk+1][lm] = bv.y; Bs[lk+2][lm] = bv.z; Bs[lk+3][lm] = bv.w;
    __syncthreads();
#pragma unroll
    for (int kk = 0; kk < 16; ++kk) {
      float4 a4 = *(const float4*)&As[kk][ty * 4];
      float4 b4 = *(const float4*)&Bs[kk][tx * 4];
      float a_[4] = {a4.x, a4.y, a4.z, a4.w};
      float b_[4] = {b4.x, b4.y, b4.z, b4.w};
#pragma unroll
      for (int i = 0; i < 4; ++i)
#pragma unroll
        for (int j = 0; j < 4; ++j)
          acc[i][j] = fmaf(a_[i], b_[j], acc[i][j]);
    }
  }
#pragma unroll
  for (int i = 0; i < 4; ++i) {
    int r = row0 + ty * 4 + i;
    if (r >= M) continue;
    size_t orow = (size_t)r;
    if (remap) orow = (r >= T_) ? (size_t)(r - T_) : (size_t)(SV_ + r);
    float* cp = C + orow * (size_t)N + col0 + tx * 4;
#pragma unroll
    for (int j = 0; j < 4; ++j) {
      float v = acc[i][j];
      if (bias) v += bias[col0 + tx * 4 + j];
      cp[j] = v;
    }
  }
}

// ---------------- im2col for conv1: A1[s][ic*3+k] = hidden[s+(k-1)*256][ic] -
__global__ void im2col1(const float* __restrict__ hid, float* __restrict__ A1)
{
  int tid = blockIdx.x * 256 + threadIdx.x;      // over SV_*DIM_
  if (tid >= SV_ * DIM_) return;
  int s = tid / DIM_, ic = tid % DIM_;
  float* dst = A1 + (size_t)s * (DIM_ * 3) + ic * 3;
#pragma unroll
  for (int k = 0; k < 3; ++k) {
    int src = s + (k - 1) * 256;
    dst[k] = (src >= 0 && src < SV_) ? hid[(size_t)src * DIM_ + ic] : 0.f;
  }
}

// ------------- im2col for conv2 with fused exact GELU on the fly -----------
__global__ void im2col2(const float* __restrict__ y1, float* __restrict__ A2)
{
  int tid = blockIdx.x * 256 + threadIdx.x;      // over SV_*RANK_
  if (tid >= SV_ * RANK_) return;
  int s = tid / RANK_, rc = tid % RANK_;
  float* dst = A2 + (size_t)s * (RANK_ * 3) + rc * 3;
#pragma unroll
  for (int k = 0; k < 3; ++k) {
    int src = s + (k - 1) * 256;
    float g = 0.f;
    if (src >= 0 && src < SV_) {
      float x = y1[(size_t)src * RANK_ + rc];
      g = 0.5f * x * (1.f + erff(x * 0.70710678118654752f));
    }
    dst[k] = g;
  }
}

// -------- per-(token,head) LayerNorm over HD=64 + RoPE on spatial tokens ----
__global__ __launch_bounds__(64) void qknorm_rope(
    float* __restrict__ Qb, float* __restrict__ Kb,
    const float* __restrict__ nq_w, const float* __restrict__ nq_b,
    const float* __restrict__ nk_w, const float* __restrict__ nk_b,
    const float* __restrict__ cosT, const float* __restrict__ sinT)
{
  int idx = blockIdx.x;                  // s*HEADS_ + h
  int s = idx / HEADS_, h = idx % HEADS_;
  int lane = threadIdx.x;                // 0..63
  float* X      = blockIdx.y ? Kb : Qb;
  const float* w = blockIdx.y ? nk_w : nq_w;
  const float* b = blockIdx.y ? nk_b : nq_b;
  size_t off = (size_t)s * DIM_ + h * HD_ + lane;
  float x = X[off];
  float m = x;
#pragma unroll
  for (int o = 32; o; o >>= 1) m += __shfl_xor(m, o);
  m *= (1.f / 64.f);
  float d = x - m;
  float v = d * d;
#pragma unroll
  for (int o = 32; o; o >>= 1) v += __shfl_xor(v, o);
  v *= (1.f / 64.f);
  float y = d * rsqrtf(v + 1e-6f) * w[lane] + b[lane];
  if (s >= T_) {
    float p = __shfl_xor(y, 1);
    float rot = (lane & 1) ? p : -p;     // x_rot[2i]=-x[2i+1]; x_rot[2i+1]=x[2i]
    int sv = s - T_;
    y = y * cosT[(size_t)sv * HD_ + lane] + rot * sinT[(size_t)sv * HD_ + lane];
  }
  X[off] = y;
}

// ---- flash attention: 1 wave per (head, 64 queries); lane owns a q-row ----
__global__ __launch_bounds__(64) void flash_attn(
    const float* __restrict__ Qb, const float* __restrict__ Kb,
    const float* __restrict__ Vb, float* __restrict__ O)
{
  int h = blockIdx.x;
  int qb = blockIdx.y;
  int lane = threadIdx.x;
  int qrow = qb * 64 + lane;
  bool valid = qrow < S_;
  int qr = valid ? qrow : (S_ - 1);
  float q[HD_];
  const float* qp = Qb + (size_t)qr * DIM_ + h * HD_;
#pragma unroll
  for (int d = 0; d < HD_; ++d) q[d] = qp[d] * 0.125f;   // fold 1/sqrt(64)
  float mx = -1e30f, l = 0.f;
  float acc[HD_];
#pragma unroll
  for (int d = 0; d < HD_; ++d) acc[d] = 0.f;
  for (int j = 0; j < S_; ++j) {
    const float4* kp4 = (const float4*)(Kb + (size_t)j * DIM_ + h * HD_);
    float s0 = 0.f, s1 = 0.f, s2 = 0.f, s3 = 0.f;
#pragma unroll
    for (int d4 = 0; d4 < HD_ / 4; ++d4) {
      float4 kv = kp4[d4];
      s0 = fmaf(q[4 * d4 + 0], kv.x, s0);
      s1 = fmaf(q[4 * d4 + 1], kv.y, s1);
      s2 = fmaf(q[4 * d4 + 2], kv.z, s2);
      s3 = fmaf(q[4 * d4 + 3], kv.w, s3);
    }
    float s = (s0 + s1) + (s2 + s3);
    if (s > mx) {                        // defer-max rescale (rare later)
      float c = __expf(mx - s);
      l *= c;
#pragma unroll
      for (int d = 0; d < HD_; ++d) acc[d] *= c;
      mx = s;
    }
    float p = __expf(s - mx);
    l += p;
    const float4* vp4 = (const float4*)(Vb + (size_t)j * DIM_ + h * HD_);
#pragma unroll
    for (int d4 = 0; d4 < HD_ / 4; ++d4) {
      float4 vv = vp4[d4];
      acc[4 * d4 + 0] = fmaf(p, vv.x, acc[4 * d4 + 0]);
      acc[4 * d4 + 1] = fmaf(p, vv.y, acc[4 * d4 + 1]);
      acc[4 * d4 + 2] = fmaf(p, vv.z, acc[4 * d4 + 2]);
      acc[4 * d4 + 3] = fmaf(p, vv.w, acc[4 * d4 + 3]);
    }
  }
  if (valid) {
    float inv = 1.f / l;
    float* op = O + (size_t)qrow * DIM_ + h * HD_;
#pragma unroll
    for (int d = 0; d < HD_; ++d) op[d] = acc[d] * inv;
  }
}

// ---------------- add conv branch into attention rows T.. -------------------
__global__ void add_cb(float* __restrict__ attn, const float* __restrict__ y2)
{
  size_t i = (size_t)blockIdx.x * 256 + threadIdx.x;   // over SV_*DIM_
  if (i < (size_t)SV_ * DIM_) attn[(size_t)T_ * DIM_ + i] += y2[i];
}

extern "C" void kernel_launch(void* const* d_in, const int* in_sizes, int n_in,
                              void* d_out, int out_size, void* d_ws, size_t ws_size,
                              hipStream_t stream)
{
  const float* hidden  = (const float*)d_in[0];
  const float* encoder = (const float*)d_in[1];
  const float* cosT    = (const float*)d_in[2];
  const float* sinT    = (const float*)d_in[3];
  const float* to_q_w  = (const float*)d_in[4];
  const float* to_q_b  = (const float*)d_in[5];
  const float* to_k_w  = (const float*)d_in[6];
  const float* to_k_b  = (const float*)d_in[7];
  const float* to_v_w  = (const float*)d_in[8];
  const float* to_v_b  = (const float*)d_in[9];
  const float* nq_w    = (const float*)d_in[10];
  const float* nq_b    = (const float*)d_in[11];
  const float* nk_w    = (const float*)d_in[12];
  const float* nk_b    = (const float*)d_in[13];
  const float* conv1_w = (const float*)d_in[14];
  const float* conv2_w = (const float*)d_in[15];
  const float* to_out_w = (const float*)d_in[16];
  const float* to_out_b = (const float*)d_in[17];
  float* out = (float*)d_out;
  float* ws  = (float*)d_ws;

  // ---- workspace layout (floats), with phase reuse ----
  float* y2   = ws;                          // SV_*DIM_        = 3,932,160
  float* base = ws + (size_t)SV_ * DIM_;
  // conv phase:
  float* A1 = base;                          // SV_*DIM_*3      = 11,796,480
  float* y1 = base + (size_t)SV_ * DIM_ * 3; // SV_*RANK_       =    262,144
  float* A2 = y1 + (size_t)SV_ * RANK_;      // SV_*RANK_*3     =    786,432
  // attention phase (reuses the conv-scratch region):
  float* hs   = base;                        // S_*DIM_
  float* Qb   = base + 1 * (size_t)S_ * DIM_;
  float* Kb   = base + 2 * (size_t)S_ * DIM_;
  float* Vb   = base + 3 * (size_t)S_ * DIM_;
  float* attn = base;                        // reuse hs region after QKV GEMMs

  // ================= conv branch =================
  im2col1<<<(SV_ * DIM_ + 255) / 256, 256, 0, stream>>>(hidden, A1);
  gemm_nt<<<dim3(RANK_ / 64, SV_ / 64), 256, 0, stream>>>(
      A1, conv1_w, nullptr, y1, SV_, RANK_, DIM_ * 3, 0);
  im2col2<<<(SV_ * RANK_ + 255) / 256, 256, 0, stream>>>(y1, A2);
  gemm_nt<<<dim3(DIM_ / 64, SV_ / 64), 256, 0, stream>>>(
      A2, conv2_w, nullptr, y2, SV_, DIM_, RANK_ * 3, 0);

  // ================= hs = concat(encoder, hidden) =================
  hipMemcpyAsync(hs, encoder, (size_t)T_ * DIM_ * sizeof(float),
                 hipMemcpyDeviceToDevice, stream);
  hipMemcpyAsync(hs + (size_t)T_ * DIM_, hidden, (size_t)SV_ * DIM_ * sizeof(float),
                 hipMemcpyDeviceToDevice, stream);

  // ================= QKV projections =================
  dim3 g_qkv(DIM_ / 64, (S_ + 63) / 64);
  gemm_nt<<<g_qkv, 256, 0, stream>>>(hs, to_q_w, to_q_b, Qb, S_, DIM_, DIM_, 0);
  gemm_nt<<<g_qkv, 256, 0, stream>>>(hs, to_k_w, to_k_b, Kb, S_, DIM_, DIM_, 0);
  gemm_nt<<<g_qkv, 256, 0, stream>>>(hs, to_v_w, to_v_b, Vb, S_, DIM_, DIM_, 0);

  // ================= LN + RoPE (in place on Q, K) =================
  qknorm_rope<<<dim3(S_ * HEADS_, 2), 64, 0, stream>>>(
      Qb, Kb, nq_w, nq_b, nk_w, nk_b, cosT, sinT);

  // ================= attention =================
  flash_attn<<<dim3(HEADS_, (S_ + 63) / 64), 64, 0, stream>>>(Qb, Kb, Vb, attn);

  // ================= + conv branch on spatial rows =================
  add_cb<<<(SV_ * DIM_ + 255) / 256, 256, 0, stream>>>(attn, y2);

  // ================= output projection, remapped into d_out ==========
  gemm_nt<<<g_qkv, 256, 0, stream>>>(attn, to_out_w, to_out_b, out, S_, DIM_, DIM_, 1);
}

// Round 2
// 3276.782 us; speedup vs baseline: 1.4823x; 1.4823x over previous
//
#include <hip/hip_runtime.h>
#include <hip/hip_bf16.h>
#include <math.h>

#define F_     8
#define DIM_   1920
#define HEADS_ 30
#define HD_    64
#define RANK_  128
#define T_     226
#define SV_    2048
#define S_     2274

#define BM 128
#define BN 128
#define BK 32

using short8 = __attribute__((ext_vector_type(8))) short;
using f32x4  = __attribute__((ext_vector_type(4))) float;

// ---- bf16 helpers (raw ushort storage) ----
__device__ __forceinline__ unsigned short f2b(float f) {
  unsigned int u = __float_as_uint(f);
  u = (u + 0x7FFFu + ((u >> 16) & 1u)) >> 16;
  return (unsigned short)u;
}
__device__ __forceinline__ float b2f(unsigned short s) {
  return __uint_as_float(((unsigned int)s) << 16);
}

// ---- async global->LDS 16B (wave-uniform base + lane*16 dest; per-lane src) ----
__device__ __forceinline__ void gload_lds16(const void* g, void* l) {
  __builtin_amdgcn_global_load_lds(
      (const __attribute__((address_space(1))) unsigned int*)g,
      (__attribute__((address_space(3))) unsigned int*)l, 16, 0, 0);
}

// ============================================================================
// MFMA bf16 GEMM:  C(MxN) = A(MxK) @ B(NxK)^T [+ bias]
// AMODE 0: A plain row-major MxK
// AMODE 1: conv 3-shift: logical col kk -> A[r + (kk/kinner)*256][kk%kinner],
//          A points at padded buffer row 0 (256 zero rows, data, 256 zero rows)
// AMODE 2: concat: row r<T_ -> A (encoder), else A2 + (r-T_) rows (hidden)
// OUTMODE 0: f32   1: bf16   2: f32 with tuple-order row remap
// ============================================================================
template<int AMODE, int OUTMODE>
__global__ __launch_bounds__(256) void gemm_mfma(
    const unsigned short* __restrict__ A,
    const unsigned short* __restrict__ A2,
    const unsigned short* __restrict__ B,
    const float* __restrict__ bias,
    void* __restrict__ Cout,
    int M, int N, int K, int kinner)
{
  __shared__ __align__(16) unsigned short As[BM * BK];
  __shared__ __align__(16) unsigned short Bs[BN * BK];
  const int t   = threadIdx.x;
  const int w   = t >> 6, l = t & 63;
  const int wr  = w >> 1, wc = w & 1;
  const int row0 = blockIdx.y * BM, col0 = blockIdx.x * BN;
  const int lr  = l & 15;          // fragment row within 16
  const int lcg = l >> 4;          // k-group 0..3
  const int sel = (lr >> 1) & 3;   // read-side swizzle selector
  const int sr  = t >> 2;          // staging row within 64-row half
  const int sc  = t & 3;           // staging 16B slot

  f32x4 acc[4][4];
#pragma unroll
  for (int i = 0; i < 4; ++i)
#pragma unroll
    for (int j = 0; j < 4; ++j) acc[i][j] = (f32x4){0.f, 0.f, 0.f, 0.f};

  for (int k0 = 0; k0 < K; k0 += BK) {
    int kseg = 0, kcol = k0;
    if constexpr (AMODE == 1) { kseg = k0 / kinner; kcol = k0 - kseg * kinner; }
#pragma unroll
    for (int it = 0; it < 2; ++it) {
      const int r    = it * 64 + sr;
      const int csrc = sc ^ ((r >> 1) & 3);   // pre-swizzled global source slot
      // ---- A ----
      int ar = row0 + r; if (ar > M - 1) ar = M - 1;
      const unsigned short* asrc;
      if constexpr (AMODE == 0) {
        asrc = A + (size_t)ar * K + k0 + csrc * 8;
      } else if constexpr (AMODE == 1) {
        asrc = A + (size_t)(ar + kseg * 256) * kinner + kcol + csrc * 8;
      } else {
        asrc = (ar < T_) ? (A  + (size_t)ar        * DIM_ + k0 + csrc * 8)
                         : (A2 + (size_t)(ar - T_) * DIM_ + k0 + csrc * 8);
      }
      gload_lds16(asrc, (char*)As + it * 4096 + t * 16);
      // ---- B ----  (N is always a multiple of 128 here)
      const unsigned short* bsrc = B + (size_t)(col0 + r) * K + k0 + csrc * 8;
      gload_lds16(bsrc, (char*)Bs + it * 4096 + t * 16);
    }
    __syncthreads();   // drains vmcnt(0): LDS DMA complete

    short8 af[4], bfv[4];
#pragma unroll
    for (int m = 0; m < 4; ++m) {
      int r = wr * 64 + m * 16 + lr;
      af[m] = *(const short8*)((const char*)As + r * 64 + ((lcg ^ sel) << 4));
    }
#pragma unroll
    for (int n = 0; n < 4; ++n) {
      int r = wc * 64 + n * 16 + lr;
      bfv[n] = *(const short8*)((const char*)Bs + r * 64 + ((lcg ^ sel) << 4));
    }
#pragma unroll
    for (int m = 0; m < 4; ++m)
#pragma unroll
      for (int n = 0; n < 4; ++n)
        acc[m][n] = __builtin_amdgcn_mfma_f32_16x16x32_bf16(af[m], bfv[n], acc[m][n], 0, 0, 0);
    __syncthreads();
  }

  // epilogue: C/D layout col = lane&15, row = (lane>>4)*4 + reg
#pragma unroll
  for (int m = 0; m < 4; ++m) {
    const int rbase = row0 + wr * 64 + m * 16 + lcg * 4;
#pragma unroll
    for (int n = 0; n < 4; ++n) {
      const int c = col0 + wc * 64 + n * 16 + lr;
      const float bi = bias ? bias[c] : 0.f;
#pragma unroll
      for (int reg = 0; reg < 4; ++reg) {
        const int r = rbase + reg;
        if (r >= M) continue;
        const float v = acc[m][n][reg] + bi;
        if constexpr (OUTMODE == 0) {
          ((float*)Cout)[(size_t)r * N + c] = v;
        } else if constexpr (OUTMODE == 1) {
          ((unsigned short*)Cout)[(size_t)r * N + c] = f2b(v);
        } else {
          const size_t orow = (r >= T_) ? (size_t)(r - T_) : (size_t)(SV_ + r);
          ((float*)Cout)[orow * N + c] = v;
        }
      }
    }
  }
}

// ============================================================================
// small conversion / packing kernels
// ============================================================================
__global__ void cvt_w(const float* __restrict__ src, unsigned short* __restrict__ dst, int n)
{
  int i = blockIdx.x * 256 + threadIdx.x;
  if (i < n) dst[i] = f2b(src[i]);
}

__global__ void hidpad_k(const float* __restrict__ hid, unsigned short* __restrict__ dst)
{
  int i = blockIdx.x * 256 + threadIdx.x;           // over 2560*1920
  if (i >= 2560 * DIM_) return;
  int r = i / DIM_;
  dst[i] = (r >= 256 && r < 256 + SV_) ? f2b(hid[i - 256 * DIM_]) : 0;
}

__global__ void encb_k(const float* __restrict__ enc, unsigned short* __restrict__ dst)
{
  int i = blockIdx.x * 256 + threadIdx.x;           // over T_*1920
  if (i < T_ * DIM_) dst[i] = f2b(enc[i]);
}

__global__ void w1p_k(const float* __restrict__ src, unsigned short* __restrict__ dst)
{
  int i = blockIdx.x * 256 + threadIdx.x;           // over 128*5760
  if (i >= RANK_ * DIM_ * 3) return;
  int oc = i / (DIM_ * 3), rem = i % (DIM_ * 3);
  int ks = rem / DIM_, ic = rem % DIM_;
  dst[i] = f2b(src[(size_t)oc * DIM_ * 3 + ic * 3 + ks]);
}

__global__ void w2p_k(const float* __restrict__ src, unsigned short* __restrict__ dst)
{
  int i = blockIdx.x * 256 + threadIdx.x;           // over 1920*384
  if (i >= DIM_ * RANK_ * 3) return;
  int oc = i / (RANK_ * 3), rem = i % (RANK_ * 3);
  int ks = rem / RANK_, rc = rem % RANK_;
  dst[i] = f2b(src[(size_t)oc * RANK_ * 3 + rc * 3 + ks]);
}

__global__ void gelupad_k(const float* __restrict__ y1, unsigned short* __restrict__ dst)
{
  int i = blockIdx.x * 256 + threadIdx.x;           // over 2560*128
  if (i >= 2560 * RANK_) return;
  int r = i / RANK_;
  unsigned short o = 0;
  if (r >= 256 && r < 256 + SV_) {
    float x = y1[i - 256 * RANK_];
    o = f2b(0.5f * x * (1.f + erff(x * 0.70710678118654752f)));
  }
  dst[i] = o;
}

__global__ void addcvt_k(const float* __restrict__ attn_f32,
                         const unsigned short* __restrict__ y2b,
                         unsigned short* __restrict__ attnb)
{
  int i = blockIdx.x * 256 + threadIdx.x;           // over S_*1920
  if (i >= S_ * DIM_) return;
  int r = i / DIM_;
  float v = attn_f32[i];
  if (r >= T_) v += b2f(y2b[i - T_ * DIM_]);
  attnb[i] = f2b(v);
}

// ---- per-(token,head) LayerNorm over HD=64 + RoPE on spatial tokens (fp32) --
__global__ __launch_bounds__(64) void qknorm_rope(
    float* __restrict__ Qb, float* __restrict__ Kb,
    const float* __restrict__ nq_w, const float* __restrict__ nq_b,
    const float* __restrict__ nk_w, const float* __restrict__ nk_b,
    const float* __restrict__ cosT, const float* __restrict__ sinT)
{
  int idx = blockIdx.x;                  // s*HEADS_ + h
  int s = idx / HEADS_, h = idx % HEADS_;
  int lane = threadIdx.x;
  float* X       = blockIdx.y ? Kb : Qb;
  const float* w = blockIdx.y ? nk_w : nq_w;
  const float* b = blockIdx.y ? nk_b : nq_b;
  size_t off = (size_t)s * DIM_ + h * HD_ + lane;
  float x = X[off];
  float m = x;
#pragma unroll
  for (int o = 32; o; o >>= 1) m += __shfl_xor(m, o);
  m *= (1.f / 64.f);
  float d = x - m;
  float v = d * d;
#pragma unroll
  for (int o = 32; o; o >>= 1) v += __shfl_xor(v, o);
  v *= (1.f / 64.f);
  float y = d * rsqrtf(v + 1e-6f) * w[lane] + b[lane];
  if (s >= T_) {
    float p = __shfl_xor(y, 1);
    float rot = (lane & 1) ? p : -p;
    int sv = s - T_;
    y = y * cosT[(size_t)sv * HD_ + lane] + rot * sinT[(size_t)sv * HD_ + lane];
  }
  X[off] = y;
}

// ---- flash attention, 4-way key-split within block; fp32 throughout --------
// O == Qb region: each block writes exactly the (rows, head-cols) rectangle it read.
__global__ __launch_bounds__(256) void flash_attn4(
    const float* __restrict__ Qb, const float* __restrict__ Kb,
    const float* __restrict__ Vb, float* __restrict__ O)
{
  __shared__ float Lml[4][64][2];
  __shared__ float Lacc[4][64][33];
  const int h = blockIdx.x, qb = blockIdx.y;
  const int t = threadIdx.x, w = t >> 6, l = t & 63;
  const int qrow = qb * 64 + l;
  const int qr = (qrow < S_) ? qrow : (S_ - 1);

  float q[HD_];
  const float4* qp = (const float4*)(Qb + (size_t)qr * DIM_ + h * HD_);
#pragma unroll
  for (int d4 = 0; d4 < HD_ / 4; ++d4) {
    float4 v = qp[d4];
    q[4*d4+0] = v.x * 0.125f; q[4*d4+1] = v.y * 0.125f;
    q[4*d4+2] = v.z * 0.125f; q[4*d4+3] = v.w * 0.125f;
  }
  const int CH = (S_ + 3) / 4;
  const int j0 = w * CH;
  const int j1 = (j0 + CH < S_) ? (j0 + CH) : S_;

  float mx = -1e30f, ll = 0.f;
  float acc[HD_];
#pragma unroll
  for (int d = 0; d < HD_; ++d) acc[d] = 0.f;

  for (int j = j0; j < j1; ++j) {
    const float4* kp4 = (const float4*)(Kb + (size_t)j * DIM_ + h * HD_);
    float s0 = 0.f, s1 = 0.f, s2 = 0.f, s3 = 0.f;
#pragma unroll
    for (int d4 = 0; d4 < HD_ / 4; ++d4) {
      float4 kv = kp4[d4];
      s0 = fmaf(q[4*d4+0], kv.x, s0);
      s1 = fmaf(q[4*d4+1], kv.y, s1);
      s2 = fmaf(q[4*d4+2], kv.z, s2);
      s3 = fmaf(q[4*d4+3], kv.w, s3);
    }
    float s = (s0 + s1) + (s2 + s3);
    if (s > mx) {
      float c = __expf(mx - s);
      ll *= c;
#pragma unroll
      for (int d = 0; d < HD_; ++d) acc[d] *= c;
      mx = s;
    }
    float p = __expf(s - mx);
    ll += p;
    const float4* vp4 = (const float4*)(Vb + (size_t)j * DIM_ + h * HD_);
#pragma unroll
    for (int d4 = 0; d4 < HD_ / 4; ++d4) {
      float4 vv = vp4[d4];
      acc[4*d4+0] = fmaf(p, vv.x, acc[4*d4+0]);
      acc[4*d4+1] = fmaf(p, vv.y, acc[4*d4+1]);
      acc[4*d4+2] = fmaf(p, vv.z, acc[4*d4+2]);
      acc[4*d4+3] = fmaf(p, vv.w, acc[4*d4+3]);
    }
  }
  Lml[w][l][0] = mx;
  Lml[w][l][1] = ll;

  const int mq = t & 63, dg = t >> 6;
  for (int p = 0; p < 2; ++p) {
    __syncthreads();
#pragma unroll
    for (int d = 0; d < 32; ++d) Lacc[w][l][d] = acc[p * 32 + d];
    __syncthreads();
    float M = Lml[0][mq][0];
#pragma unroll
    for (int ww = 1; ww < 4; ++ww) M = fmaxf(M, Lml[ww][mq][0]);
    float sc[4]; float L = 0.f;
#pragma unroll
    for (int ww = 0; ww < 4; ++ww) {
      sc[ww] = __expf(Lml[ww][mq][0] - M);
      L = fmaf(sc[ww], Lml[ww][mq][1], L);
    }
    const float invL = 1.f / L;
    const int orow = qb * 64 + mq;
    if (orow < S_) {
      float* op = O + (size_t)orow * DIM_ + h * HD_ + p * 32 + dg * 8;
#pragma unroll
      for (int d = 0; d < 8; ++d) {
        int di = dg * 8 + d;
        float s = sc[0] * Lacc[0][mq][di];
        s = fmaf(sc[1], Lacc[1][mq][di], s);
        s = fmaf(sc[2], Lacc[2][mq][di], s);
        s = fmaf(sc[3], Lacc[3][mq][di], s);
        op[d] = s * invL;
      }
    }
  }
}

// ============================================================================
extern "C" void kernel_launch(void* const* d_in, const int* in_sizes, int n_in,
                              void* d_out, int out_size, void* d_ws, size_t ws_size,
                              hipStream_t stream)
{
  const float* hidden  = (const float*)d_in[0];
  const float* encoder = (const float*)d_in[1];
  const float* cosT    = (const float*)d_in[2];
  const float* sinT    = (const float*)d_in[3];
  const float* to_q_w  = (const float*)d_in[4];
  const float* to_q_b  = (const float*)d_in[5];
  const float* to_k_w  = (const float*)d_in[6];
  const float* to_k_b  = (const float*)d_in[7];
  const float* to_v_w  = (const float*)d_in[8];
  const float* to_v_b  = (const float*)d_in[9];
  const float* nq_w    = (const float*)d_in[10];
  const float* nq_b    = (const float*)d_in[11];
  const float* nk_w    = (const float*)d_in[12];
  const float* nk_b    = (const float*)d_in[13];
  const float* conv1_w = (const float*)d_in[14];
  const float* conv2_w = (const float*)d_in[15];
  const float* to_out_w = (const float*)d_in[16];
  const float* to_out_b = (const float*)d_in[17];
  float* out = (float*)d_out;

  // ---- workspace layout (bytes); peak 80.03 MB (round-0 proved >= 85.58 MB) ----
  char* p = (char*)d_ws;
  unsigned short* hidpad = (unsigned short*)p;           p += (size_t)2560 * DIM_ * 2;   // 9,830,400
  unsigned short* y2b    = (unsigned short*)p;           p += (size_t)SV_ * DIM_ * 2;    // 7,864,320
  unsigned short* wbuf   = (unsigned short*)p;           p += (size_t)DIM_ * DIM_ * 2;   // 7,372,800
  float*          Qb     = (float*)p;                    p += (size_t)S_ * DIM_ * 4;     // 17,464,320
  float*          Kb     = (float*)p;                    p += (size_t)S_ * DIM_ * 4;
  float*          Vb     = (float*)p;                    p += (size_t)S_ * DIM_ * 4;
  unsigned short* encb   = (unsigned short*)p;           p += (size_t)T_ * DIM_ * 2;     // 867,840
  float*          y1     = (float*)p;                    p += (size_t)SV_ * RANK_ * 4;   // 1,048,576
  unsigned short* gelupad= (unsigned short*)p;           p += (size_t)2560 * RANK_ * 2;  // 655,360
  unsigned short* attnb  = (unsigned short*)Kb;          // overlays Kb after flash
  float*          attnf  = Qb;                           // flash writes its output over Q

  // ================= input conversions =================
  hidpad_k<<<(2560 * DIM_ + 255) / 256, 256, 0, stream>>>(hidden, hidpad);
  encb_k<<<(T_ * DIM_ + 255) / 256, 256, 0, stream>>>(encoder, encb);

  // ================= conv branch =================
  w1p_k<<<(RANK_ * DIM_ * 3 + 255) / 256, 256, 0, stream>>>(conv1_w, wbuf);
  gemm_mfma<1, 0><<<dim3(RANK_ / BN, SV_ / BM), 256, 0, stream>>>(
      hidpad, nullptr, wbuf, nullptr, y1, SV_, RANK_, DIM_ * 3, DIM_);
  gelupad_k<<<(2560 * RANK_ + 255) / 256, 256, 0, stream>>>(y1, gelupad);
  w2p_k<<<(DIM_ * RANK_ * 3 + 255) / 256, 256, 0, stream>>>(conv2_w, wbuf);
  gemm_mfma<1, 1><<<dim3(DIM_ / BN, SV_ / BM), 256, 0, stream>>>(
      gelupad, nullptr, wbuf, nullptr, y2b, SV_, DIM_, RANK_ * 3, RANK_);

  // ================= QKV projections =================
  const unsigned short* hid0 = hidpad + (size_t)256 * DIM_;  // hidden row 0
  dim3 gq(DIM_ / BN, (S_ + BM - 1) / BM);
  cvt_w<<<(DIM_ * DIM_ + 255) / 256, 256, 0, stream>>>(to_q_w, wbuf, DIM_ * DIM_);
  gemm_mfma<2, 0><<<gq, 256, 0, stream>>>(encb, hid0, wbuf, to_q_b, Qb, S_, DIM_, DIM_, 0);
  cvt_w<<<(DIM_ * DIM_ + 255) / 256, 256, 0, stream>>>(to_k_w, wbuf, DIM_ * DIM_);
  gemm_mfma<2, 0><<<gq, 256, 0, stream>>>(encb, hid0, wbuf, to_k_b, Kb, S_, DIM_, DIM_, 0);
  cvt_w<<<(DIM_ * DIM_ + 255) / 256, 256, 0, stream>>>(to_v_w, wbuf, DIM_ * DIM_);
  gemm_mfma<2, 0><<<gq, 256, 0, stream>>>(encb, hid0, wbuf, to_v_b, Vb, S_, DIM_, DIM_, 0);

  // ================= LN + RoPE (in place, fp32) =================
  qknorm_rope<<<dim3(S_ * HEADS_, 2), 64, 0, stream>>>(
      Qb, Kb, nq_w, nq_b, nk_w, nk_b, cosT, sinT);

  // ================= attention (writes fp32 into Qb) =================
  flash_attn4<<<dim3(HEADS_, (S_ + 63) / 64), 256, 0, stream>>>(Qb, Kb, Vb, attnf);

  // ======== add conv branch + convert to bf16 (into Kb region) ========
  addcvt_k<<<(S_ * DIM_ + 255) / 256, 256, 0, stream>>>(attnf, y2b, attnb);

  // ================= output projection -> d_out (remapped) =================
  cvt_w<<<(DIM_ * DIM_ + 255) / 256, 256, 0, stream>>>(to_out_w, wbuf, DIM_ * DIM_);
  gemm_mfma<0, 2><<<gq, 256, 0, stream>>>(attnb, nullptr, wbuf, to_out_b, out, S_, DIM_, DIM_, 0);
}

// Round 3
// 502.657 us; speedup vs baseline: 9.6628x; 6.5189x over previous
//
#include <hip/hip_runtime.h>
#include <hip/hip_bf16.h>
#include <math.h>

#define F_     8
#define DIM_   1920
#define HEADS_ 30
#define HD_    64
#define RANK_  128
#define T_     226
#define SV_    2048
#define S_     2274

#define BM 128
#define BN 128
#define BK 32

using short8 = __attribute__((ext_vector_type(8))) short;
using f32x4  = __attribute__((ext_vector_type(4))) float;

__device__ __forceinline__ unsigned short f2b(float f) {
  unsigned int u = __float_as_uint(f);
  u = (u + 0x7FFFu + ((u >> 16) & 1u)) >> 16;
  return (unsigned short)u;
}
__device__ __forceinline__ float b2f(unsigned short s) {
  return __uint_as_float(((unsigned int)s) << 16);
}
__device__ __forceinline__ void gload_lds16(const void* g, void* l) {
  __builtin_amdgcn_global_load_lds(
      (const __attribute__((address_space(1))) unsigned int*)g,
      (__attribute__((address_space(3))) unsigned int*)l, 16, 0, 0);
}

// ============================================================================
// MFMA bf16 GEMM:  C(MxN) = A(MxK) @ B(NxK)^T [+ bias]
// AMODE 0: A plain row-major, stride lda
// AMODE 1: conv shifts: col kk -> A[r + (kk/kinner)*256][kk%kinner]
// AMODE 2: concat rows: r<T_ -> A, else A2+(r-T_); lda=DIM_
// AMODE 3: conv1 split-K: z=blockIdx.z: A+=z*1920 (lda), B+=z*256*DIM_ (ldb),
//          Cout = (float*)Cout + z*M*N
// OUTMODE 0: f32  1: bf16  2: f32 tuple-remap  3: bf16 QKV col-split
// ============================================================================
template<int AMODE, int OUTMODE>
__global__ __launch_bounds__(256) void gemm_mfma(
    const unsigned short* __restrict__ A,
    const unsigned short* __restrict__ A2,
    const unsigned short* __restrict__ B,
    const float* __restrict__ bias,
    void* __restrict__ Cout,
    int M, int N, int K, int lda, int ldb, int kinner)
{
  __shared__ __align__(16) unsigned short As[BM * BK];
  __shared__ __align__(16) unsigned short Bs[BN * BK];
  if constexpr (AMODE == 3) {
    const int z = blockIdx.z;
    A += (size_t)z * 1920;
    B += (size_t)z * 256 * DIM_;
    Cout = (void*)((float*)Cout + (size_t)z * M * N);
  }
  const int t   = threadIdx.x;
  const int w   = t >> 6, l = t & 63;
  const int wr  = w >> 1, wc = w & 1;
  const int row0 = blockIdx.y * BM, col0 = blockIdx.x * BN;
  const int lr  = l & 15;
  const int lcg = l >> 4;
  const int sel = (lr >> 1) & 3;
  const int sr  = t >> 2;
  const int sc  = t & 3;

  f32x4 acc[4][4];
#pragma unroll
  for (int i = 0; i < 4; ++i)
#pragma unroll
    for (int j = 0; j < 4; ++j) acc[i][j] = (f32x4){0.f, 0.f, 0.f, 0.f};

  for (int k0 = 0; k0 < K; k0 += BK) {
    int kseg = 0, kcol = k0;
    if constexpr (AMODE == 1) { kseg = k0 / kinner; kcol = k0 - kseg * kinner; }
#pragma unroll
    for (int it = 0; it < 2; ++it) {
      const int r    = it * 64 + sr;
      const int csrc = sc ^ ((r >> 1) & 3);
      int ar = row0 + r; if (ar > M - 1) ar = M - 1;
      const unsigned short* asrc;
      if constexpr (AMODE == 1) {
        asrc = A + (size_t)(ar + kseg * 256) * kinner + kcol + csrc * 8;
      } else if constexpr (AMODE == 2) {
        asrc = (ar < T_) ? (A  + (size_t)ar        * DIM_ + k0 + csrc * 8)
                         : (A2 + (size_t)(ar - T_) * DIM_ + k0 + csrc * 8);
      } else {
        asrc = A + (size_t)ar * lda + k0 + csrc * 8;
      }
      gload_lds16(asrc, (char*)As + it * 4096 + t * 16);
      const unsigned short* bsrc = B + (size_t)(col0 + r) * ldb + k0 + csrc * 8;
      gload_lds16(bsrc, (char*)Bs + it * 4096 + t * 16);
    }
    __syncthreads();

    short8 af[4], bfv[4];
#pragma unroll
    for (int m = 0; m < 4; ++m) {
      int r = wr * 64 + m * 16 + lr;
      af[m] = *(const short8*)((const char*)As + r * 64 + ((lcg ^ sel) << 4));
    }
#pragma unroll
    for (int n = 0; n < 4; ++n) {
      int r = wc * 64 + n * 16 + lr;
      bfv[n] = *(const short8*)((const char*)Bs + r * 64 + ((lcg ^ sel) << 4));
    }
#pragma unroll
    for (int m = 0; m < 4; ++m)
#pragma unroll
      for (int n = 0; n < 4; ++n)
        acc[m][n] = __builtin_amdgcn_mfma_f32_16x16x32_bf16(af[m], bfv[n], acc[m][n], 0, 0, 0);
    __syncthreads();
  }

#pragma unroll
  for (int m = 0; m < 4; ++m) {
    const int rbase = row0 + wr * 64 + m * 16 + lcg * 4;
#pragma unroll
    for (int n = 0; n < 4; ++n) {
      const int c = col0 + wc * 64 + n * 16 + lr;
      const float bi = bias ? bias[c] : 0.f;
#pragma unroll
      for (int reg = 0; reg < 4; ++reg) {
        const int r = rbase + reg;
        if (r >= M) continue;
        const float v = acc[m][n][reg] + bi;
        if constexpr (OUTMODE == 0) {
          ((float*)Cout)[(size_t)r * N + c] = v;
        } else if constexpr (OUTMODE == 1) {
          ((unsigned short*)Cout)[(size_t)r * N + c] = f2b(v);
        } else if constexpr (OUTMODE == 2) {
          const size_t orow = (r >= T_) ? (size_t)(r - T_) : (size_t)(SV_ + r);
          ((float*)Cout)[orow * N + c] = v;
        } else {
          const int buf = c / DIM_, cc = c - buf * DIM_;
          ((unsigned short*)Cout)[(size_t)buf * S_ * DIM_ + (size_t)r * DIM_ + cc] = f2b(v);
        }
      }
    }
  }
}

// ============================================================================
// MFMA flash attention. Block: 4 waves x 16 q-rows; KV tiles of 64.
// All bf16 inputs (Q pre-scaled 1/8); O bf16 written in place over Qbb.
// ============================================================================
__global__ __launch_bounds__(256) void attn_mfma(
    const unsigned short* __restrict__ Qbb,
    const unsigned short* __restrict__ Kbb,
    const unsigned short* __restrict__ Vbb,
    unsigned short* __restrict__ O)
{
  __shared__ __align__(16) unsigned short Kl[64 * 64];   // [key][d], swz
  __shared__ __align__(16) unsigned short Vt[64 * 64];   // [d][key], swz
  __shared__ __align__(16) unsigned short Pl[4][16 * 64];// per-wave [q][key], swz

  const int qb = blockIdx.x, h = blockIdx.y;
  const int t = threadIdx.x, w = t >> 6, l = t & 63;
  const int lr = l & 15, lg = l >> 4;
  const int q0 = qb * 64;

  // Q fragments (held for whole kernel)
  short8 qa[2];
  {
    int qrow = q0 + w * 16 + lr; if (qrow >= S_) qrow = S_ - 1;
    const unsigned short* qp = Qbb + (size_t)qrow * DIM_ + h * 64 + lg * 8;
    qa[0] = *(const short8*)qp;
    qa[1] = *(const short8*)(qp + 32);
  }

  f32x4 oacc[4];
#pragma unroll
  for (int n = 0; n < 4; ++n) oacc[n] = (f32x4){0.f, 0.f, 0.f, 0.f};
  f32x4 m_run = (f32x4){-1e30f, -1e30f, -1e30f, -1e30f};
  f32x4 l_run = (f32x4){0.f, 0.f, 0.f, 0.f};

  const int NT = (S_ + 63) / 64;
  for (int jt = 0; jt < NT; ++jt) {
    const int j0 = jt * 64;
    __syncthreads();                       // prev tile's reads complete
    // ---- stage K tile via global_load_lds (linear dest, pre-swz source) ----
#pragma unroll
    for (int it = 0; it < 2; ++it) {
      const int row = (t >> 3) + it * 32;
      int key = j0 + row; if (key >= S_) key = S_ - 1;
      const int cofs = (((t & 7) * 16) ^ ((row & 7) << 4)) >> 1;  // ushorts
      gload_lds16(Kbb + (size_t)key * DIM_ + h * 64 + cofs,
                  (char*)Kl + it * 4096 + t * 16);
    }
    // ---- stage V transposed: wave w owns dims w*16..w*16+15, key = l ----
    {
      int key = j0 + l; if (key >= S_) key = S_ - 1;
      const unsigned short* vp = Vbb + (size_t)key * DIM_ + h * 64 + w * 16;
      short8 v0 = *(const short8*)vp;
      short8 v1 = *(const short8*)(vp + 8);
#pragma unroll
      for (int i = 0; i < 8; ++i)
        Vt[(w * 16 + i) * 64 + (l ^ ((i & 7) << 3))] = (unsigned short)v0[i];
#pragma unroll
      for (int i = 8; i < 16; ++i)
        Vt[(w * 16 + i) * 64 + (l ^ ((i & 7) << 3))] = (unsigned short)v1[i - 8];
    }
    __syncthreads();                       // staging visible (vmcnt drained)

    // ---- S = Q @ K^T : lane holds S[q=lg*4+reg][key=m*16+lr] ----
    f32x4 sacc[4];
#pragma unroll
    for (int m = 0; m < 4; ++m) sacc[m] = (f32x4){0.f, 0.f, 0.f, 0.f};
#pragma unroll
    for (int m = 0; m < 4; ++m) {
#pragma unroll
      for (int ks = 0; ks < 2; ++ks) {
        const short8 kb = *(const short8*)((const char*)Kl + (m * 16 + lr) * 128 +
                              ((ks * 64 + lg * 16) ^ ((lr & 7) << 4)));
        sacc[m] = __builtin_amdgcn_mfma_f32_16x16x32_bf16(qa[ks], kb, sacc[m], 0, 0, 0);
      }
    }
    if (j0 + 64 > S_) {                    // mask invalid keys (last tile)
#pragma unroll
      for (int m = 0; m < 4; ++m)
        if (j0 + m * 16 + lr >= S_) {
#pragma unroll
          for (int r = 0; r < 4; ++r) sacc[m][r] = -1e30f;
        }
    }

    // ---- online softmax ----
    f32x4 mx = sacc[0];
#pragma unroll
    for (int m = 1; m < 4; ++m)
#pragma unroll
      for (int r = 0; r < 4; ++r) mx[r] = fmaxf(mx[r], sacc[m][r]);
#pragma unroll
    for (int off = 1; off < 16; off <<= 1)
#pragma unroll
      for (int r = 0; r < 4; ++r) mx[r] = fmaxf(mx[r], __shfl_xor(mx[r], off));

    f32x4 mnew, scale;
#pragma unroll
    for (int r = 0; r < 4; ++r) {
      mnew[r]  = fmaxf(m_run[r], mx[r]);
      scale[r] = __expf(m_run[r] - mnew[r]);
    }
    m_run = mnew;

    f32x4 rs = (f32x4){0.f, 0.f, 0.f, 0.f};
#pragma unroll
    for (int m = 0; m < 4; ++m)
#pragma unroll
      for (int r = 0; r < 4; ++r) {
        const float p = __expf(sacc[m][r] - mnew[r]);
        rs[r] += p;
        const int prow = lg * 4 + r;
        Pl[w][prow * 64 + ((m * 16 + lr) ^ ((prow & 7) << 3))] = f2b(p);
      }
#pragma unroll
    for (int off = 1; off < 16; off <<= 1)
#pragma unroll
      for (int r = 0; r < 4; ++r) rs[r] += __shfl_xor(rs[r], off);
#pragma unroll
    for (int r = 0; r < 4; ++r) l_run[r] = l_run[r] * scale[r] + rs[r];
#pragma unroll
    for (int n = 0; n < 4; ++n)
#pragma unroll
      for (int r = 0; r < 4; ++r) oacc[n][r] *= scale[r];

    // ---- O += P @ V (V^T rows in LDS) ----
#pragma unroll
    for (int ks = 0; ks < 2; ++ks) {
      const short8 pa = *(const short8*)((const char*)Pl[w] + lr * 128 +
                            ((ks * 64 + lg * 16) ^ ((lr & 7) << 4)));
#pragma unroll
      for (int n = 0; n < 4; ++n) {
        const short8 vb = *(const short8*)((const char*)Vt + (n * 16 + lr) * 128 +
                              ((ks * 64 + lg * 16) ^ ((lr & 7) << 4)));
        oacc[n] = __builtin_amdgcn_mfma_f32_16x16x32_bf16(pa, vb, oacc[n], 0, 0, 0);
      }
    }
  }

  // ---- epilogue: divide by l, store bf16 into O (same rectangle as Q) ----
#pragma unroll
  for (int r = 0; r < 4; ++r) {
    const float invl = 1.f / l_run[r];
    const int row = q0 + w * 16 + lg * 4 + r;
    if (row >= S_) continue;
#pragma unroll
    for (int n = 0; n < 4; ++n)
      O[(size_t)row * DIM_ + h * 64 + n * 16 + lr] = f2b(oacc[n][r] * invl);
  }
}

// ============================================================================
// small kernels
// ============================================================================
__global__ void cvt_w(const float* __restrict__ src, unsigned short* __restrict__ dst, int n)
{
  int i = blockIdx.x * 256 + threadIdx.x;
  if (i < n) dst[i] = f2b(src[i]);
}

__global__ void hidpad_k(const float* __restrict__ hid, unsigned short* __restrict__ dst)
{
  int i = blockIdx.x * 256 + threadIdx.x;
  if (i >= 2560 * DIM_) return;
  int r = i / DIM_;
  dst[i] = (r >= 256 && r < 256 + SV_) ? f2b(hid[i - 256 * DIM_]) : 0;
}

__global__ void encb_k(const float* __restrict__ enc, unsigned short* __restrict__ dst)
{
  int i = blockIdx.x * 256 + threadIdx.x;
  if (i < T_ * DIM_) dst[i] = f2b(enc[i]);
}

__global__ void w1p_k(const float* __restrict__ src, unsigned short* __restrict__ dst)
{
  int i = blockIdx.x * 256 + threadIdx.x;           // over 128*5760
  if (i >= RANK_ * DIM_ * 3) return;
  int oc = i / (DIM_ * 3), rem = i % (DIM_ * 3);
  int ks = rem / DIM_, ic = rem % DIM_;
  dst[i] = f2b(src[(size_t)oc * DIM_ * 3 + ic * 3 + ks]);
}

__global__ void w2p_k(const float* __restrict__ src, unsigned short* __restrict__ dst)
{
  int i = blockIdx.x * 256 + threadIdx.x;           // over 1920*384
  if (i >= DIM_ * RANK_ * 3) return;
  int oc = i / (RANK_ * 3), rem = i % (RANK_ * 3);
  int ks = rem / RANK_, rc = rem % RANK_;
  dst[i] = f2b(src[(size_t)oc * RANK_ * 3 + rc * 3 + ks]);
}

__global__ void wqkv_k(const float* __restrict__ q, const float* __restrict__ k,
                       const float* __restrict__ v, unsigned short* __restrict__ dst)
{
  int i = blockIdx.x * 256 + threadIdx.x;           // over 3*DIM*DIM
  if (i >= 3 * DIM_ * DIM_) return;
  int which = i / (DIM_ * DIM_), j = i % (DIM_ * DIM_);
  const float* s = which == 0 ? q : which == 1 ? k : v;
  dst[i] = f2b(s[j]);
}

__global__ void bqkv_k(const float* __restrict__ q, const float* __restrict__ k,
                       const float* __restrict__ v, float* __restrict__ dst)
{
  int i = blockIdx.x * 256 + threadIdx.x;           // over 3*DIM
  if (i >= 3 * DIM_) return;
  int which = i / DIM_, j = i % DIM_;
  dst[i] = which == 0 ? q[j] : which == 1 ? k[j] : v[j];
}

// sum 3 split-K partials of y1^T [128][2048], GELU, write padded [2560][128]
__global__ void gelupad_k(const float* __restrict__ y1T, unsigned short* __restrict__ dst)
{
  int i = blockIdx.x * 256 + threadIdx.x;           // over 2560*128
  if (i >= 2560 * RANK_) return;
  int r = i / RANK_, rc = i % RANK_;
  unsigned short o = 0;
  if (r >= 256 && r < 256 + SV_) {
    int s = r - 256;
    float x = y1T[(size_t)rc * SV_ + s]
            + y1T[(size_t)RANK_ * SV_ + (size_t)rc * SV_ + s]
            + y1T[(size_t)2 * RANK_ * SV_ + (size_t)rc * SV_ + s];
    o = f2b(0.5f * x * (1.f + erff(x * 0.70710678118654752f)));
  }
  dst[i] = o;
}

__global__ void addcvt_k(const unsigned short* __restrict__ Ob,
                         const unsigned short* __restrict__ y2b,
                         unsigned short* __restrict__ attnb)
{
  int i = blockIdx.x * 256 + threadIdx.x;           // over S_*DIM_
  if (i >= S_ * DIM_) return;
  int r = i / DIM_;
  float v = b2f(Ob[i]);
  if (r >= T_) v += b2f(y2b[i - T_ * DIM_]);
  attnb[i] = f2b(v);
}

// LN over HD=64 + RoPE, bf16 in place; Q branch scaled by 1/8
__global__ __launch_bounds__(256) void qknorm_rope(
    unsigned short* __restrict__ Qbb, unsigned short* __restrict__ Kbb,
    const float* __restrict__ nq_w, const float* __restrict__ nq_b,
    const float* __restrict__ nk_w, const float* __restrict__ nk_b,
    const float* __restrict__ cosT, const float* __restrict__ sinT)
{
  const int w = threadIdx.x >> 6, lane = threadIdx.x & 63;
  const int idx = blockIdx.x * 4 + w;
  if (idx >= S_ * HEADS_) return;
  const int s = idx / HEADS_, h = idx % HEADS_;
  unsigned short* X = blockIdx.y ? Kbb : Qbb;
  const float* wt = blockIdx.y ? nk_w : nq_w;
  const float* bt = blockIdx.y ? nk_b : nq_b;
  const size_t off = (size_t)s * DIM_ + h * HD_ + lane;
  float x = b2f(X[off]);
  float m = x;
#pragma unroll
  for (int o = 32; o; o >>= 1) m += __shfl_xor(m, o);
  m *= (1.f / 64.f);
  float d = x - m;
  float v = d * d;
#pragma unroll
  for (int o = 32; o; o >>= 1) v += __shfl_xor(v, o);
  v *= (1.f / 64.f);
  float y = d * rsqrtf(v + 1e-6f) * wt[lane] + bt[lane];
  if (s >= T_) {
    float p = __shfl_xor(y, 1);
    float rot = (lane & 1) ? p : -p;
    int sv = s - T_;
    y = y * cosT[(size_t)sv * HD_ + lane] + rot * sinT[(size_t)sv * HD_ + lane];
  }
  if (!blockIdx.y) y *= 0.125f;
  X[off] = f2b(y);
}

// ============================================================================
extern "C" void kernel_launch(void* const* d_in, const int* in_sizes, int n_in,
                              void* d_out, int out_size, void* d_ws, size_t ws_size,
                              hipStream_t stream)
{
  const float* hidden  = (const float*)d_in[0];
  const float* encoder = (const float*)d_in[1];
  const float* cosT    = (const float*)d_in[2];
  const float* sinT    = (const float*)d_in[3];
  const float* to_q_w  = (const float*)d_in[4];
  const float* to_q_b  = (const float*)d_in[5];
  const float* to_k_w  = (const float*)d_in[6];
  const float* to_k_b  = (const float*)d_in[7];
  const float* to_v_w  = (const float*)d_in[8];
  const float* to_v_b  = (const float*)d_in[9];
  const float* nq_w    = (const float*)d_in[10];
  const float* nq_b    = (const float*)d_in[11];
  const float* nk_w    = (const float*)d_in[12];
  const float* nk_b    = (const float*)d_in[13];
  const float* conv1_w = (const float*)d_in[14];
  const float* conv2_w = (const float*)d_in[15];
  const float* to_out_w = (const float*)d_in[16];
  const float* to_out_b = (const float*)d_in[17];
  float* out = (float*)d_out;

  // ---- workspace layout (~71.4 MB; 80 MB proven available) ----
  char* p = (char*)d_ws;
  unsigned short* hidpad = (unsigned short*)p;  p += (size_t)2560 * DIM_ * 2;        // 9.83 MB
  unsigned short* y2b    = (unsigned short*)p;  p += (size_t)SV_ * DIM_ * 2;         // 7.86 MB
  unsigned short* wqkv   = (unsigned short*)p;  p += (size_t)3 * DIM_ * DIM_ * 2;    // 22.1 MB
  unsigned short* QKVbb  = (unsigned short*)p;  p += (size_t)3 * S_ * DIM_ * 2;      // 26.2 MB
  unsigned short* encb   = (unsigned short*)p;  p += (size_t)T_ * DIM_ * 2;          // 0.87 MB
  float*          y1T    = (float*)p;           p += (size_t)3 * RANK_ * SV_ * 4;    // 3.15 MB
  unsigned short* gelup  = (unsigned short*)p;  p += (size_t)2560 * RANK_ * 2;       // 0.66 MB
  float*          bqkv   = (float*)p;           p += (size_t)3 * DIM_ * 4;           // 23 KB
  unsigned short* Qbb = QKVbb;
  unsigned short* Kbb = QKVbb + (size_t)S_ * DIM_;
  unsigned short* Vbb = QKVbb + (size_t)2 * S_ * DIM_;
  unsigned short* attnb = Kbb;                  // post-attn reuse

  // ---- input conversions ----
  hidpad_k<<<(2560 * DIM_ + 255) / 256, 256, 0, stream>>>(hidden, hidpad);
  encb_k<<<(T_ * DIM_ + 255) / 256, 256, 0, stream>>>(encoder, encb);

  // ---- conv branch ----
  w1p_k<<<(RANK_ * DIM_ * 3 + 255) / 256, 256, 0, stream>>>(conv1_w, wqkv);
  gemm_mfma<3, 0><<<dim3(SV_ / BN, 1, 3), 256, 0, stream>>>(
      wqkv, nullptr, hidpad, nullptr, y1T, RANK_, SV_, DIM_, DIM_ * 3, DIM_, 1);
  gelupad_k<<<(2560 * RANK_ + 255) / 256, 256, 0, stream>>>(y1T, gelup);
  w2p_k<<<(DIM_ * RANK_ * 3 + 255) / 256, 256, 0, stream>>>(conv2_w, wqkv);
  gemm_mfma<1, 1><<<dim3(DIM_ / BN, SV_ / BM), 256, 0, stream>>>(
      gelup, nullptr, wqkv, nullptr, y2b, SV_, DIM_, RANK_ * 3, RANK_ * 3, RANK_ * 3, RANK_);

  // ---- fused QKV projection (bf16 out) ----
  wqkv_k<<<(3 * DIM_ * DIM_ + 255) / 256, 256, 0, stream>>>(to_q_w, to_k_w, to_v_w, wqkv);
  bqkv_k<<<(3 * DIM_ + 255) / 256, 256, 0, stream>>>(to_q_b, to_k_b, to_v_b, bqkv);
  const unsigned short* hid0 = hidpad + (size_t)256 * DIM_;
  gemm_mfma<2, 3><<<dim3(3 * DIM_ / BN, (S_ + BM - 1) / BM), 256, 0, stream>>>(
      encb, hid0, wqkv, bqkv, QKVbb, S_, 3 * DIM_, DIM_, DIM_, DIM_, 1);

  // ---- LN + RoPE (bf16 in place; Q scaled 1/8) ----
  qknorm_rope<<<dim3((S_ * HEADS_ + 3) / 4, 2), 256, 0, stream>>>(
      Qbb, Kbb, nq_w, nq_b, nk_w, nk_b, cosT, sinT);

  // ---- MFMA flash attention (O bf16 over Qbb) ----
  attn_mfma<<<dim3((S_ + 63) / 64, HEADS_), 256, 0, stream>>>(Qbb, Kbb, Vbb, Qbb);

  // ---- add conv branch (bf16) ----
  addcvt_k<<<(S_ * DIM_ + 255) / 256, 256, 0, stream>>>(Qbb, y2b, attnb);

  // ---- output projection -> d_out (fp32, tuple remap) ----
  cvt_w<<<(DIM_ * DIM_ + 255) / 256, 256, 0, stream>>>(to_out_w, wqkv, DIM_ * DIM_);
  gemm_mfma<0, 2><<<dim3(DIM_ / BN, (S_ + BM - 1) / BM), 256, 0, stream>>>(
      attnb, nullptr, wqkv, to_out_b, out, S_, DIM_, DIM_, DIM_, DIM_, 1);
}

// Round 4
// 459.302 us; speedup vs baseline: 10.5749x; 1.0944x over previous
//
#include <hip/hip_runtime.h>
#include <hip/hip_bf16.h>
#include <math.h>

#define F_     8
#define DIM_   1920
#define HEADS_ 30
#define HD_    64
#define RANK_  128
#define T_     226
#define SV_    2048
#define S_     2274

#define BM 128
#define BN 128
#define BK 32

using short8 = __attribute__((ext_vector_type(8))) short;
using f32x4  = __attribute__((ext_vector_type(4))) float;
using i32x4v = __attribute__((ext_vector_type(4))) int;

__device__ __forceinline__ unsigned short f2b(float f) {
  unsigned int u = __float_as_uint(f);
  u = (u + 0x7FFFu + ((u >> 16) & 1u)) >> 16;
  return (unsigned short)u;
}
__device__ __forceinline__ float b2f(unsigned short s) {
  return __uint_as_float(((unsigned int)s) << 16);
}
__device__ __forceinline__ void gload_lds16(const void* g, void* l) {
  __builtin_amdgcn_global_load_lds(
      (const __attribute__((address_space(1))) unsigned int*)g,
      (__attribute__((address_space(3))) unsigned int*)l, 16, 0, 0);
}

// ============================================================================
// MFMA bf16 GEMM:  C(MxN) = A(MxK) @ B(NxK)^T [+ bias]
// AMODE 0: A plain row-major, stride lda
// AMODE 1: conv shifts: col kk -> A[r + (kk/kinner)*256][kk%kinner]
// AMODE 2: concat rows: r<T_ -> A, else A2+(r-T_); lda=DIM_
// AMODE 3: conv1 split-K x12: z: A+=z*480 (1920=4*480), B row += (z>>2)*256,
//          B col += (z&3)*480, Cout partial z. Launch with K=480.
// OUTMODE 0: f32  1: bf16  2: f32 tuple-remap  3: bf16 QKV col-split
// ============================================================================
template<int AMODE, int OUTMODE>
__global__ __launch_bounds__(256) void gemm_mfma(
    const unsigned short* __restrict__ A,
    const unsigned short* __restrict__ A2,
    const unsigned short* __restrict__ B,
    const float* __restrict__ bias,
    void* __restrict__ Cout,
    int M, int N, int K, int lda, int ldb, int kinner)
{
  __shared__ __align__(16) unsigned short As[BM * BK];
  __shared__ __align__(16) unsigned short Bs[BN * BK];
  if constexpr (AMODE == 3) {
    const int z = blockIdx.z;
    A += (size_t)z * 480;
    B += (size_t)(z >> 2) * 256 * DIM_ + (z & 3) * 480;
    Cout = (void*)((float*)Cout + (size_t)z * M * N);
  }
  const int t   = threadIdx.x;
  const int w   = t >> 6, l = t & 63;
  const int wr  = w >> 1, wc = w & 1;
  const int row0 = blockIdx.y * BM, col0 = blockIdx.x * BN;
  const int lr  = l & 15;
  const int lcg = l >> 4;
  const int sel = (lr >> 1) & 3;
  const int sr  = t >> 2;
  const int sc  = t & 3;

  f32x4 acc[4][4];
#pragma unroll
  for (int i = 0; i < 4; ++i)
#pragma unroll
    for (int j = 0; j < 4; ++j) acc[i][j] = (f32x4){0.f, 0.f, 0.f, 0.f};

  for (int k0 = 0; k0 < K; k0 += BK) {
    int kseg = 0, kcol = k0;
    if constexpr (AMODE == 1) { kseg = k0 / kinner; kcol = k0 - kseg * kinner; }
#pragma unroll
    for (int it = 0; it < 2; ++it) {
      const int r    = it * 64 + sr;
      const int csrc = sc ^ ((r >> 1) & 3);
      int ar = row0 + r; if (ar > M - 1) ar = M - 1;
      const unsigned short* asrc;
      if constexpr (AMODE == 1) {
        asrc = A + (size_t)(ar + kseg * 256) * kinner + kcol + csrc * 8;
      } else if constexpr (AMODE == 2) {
        asrc = (ar < T_) ? (A  + (size_t)ar        * DIM_ + k0 + csrc * 8)
                         : (A2 + (size_t)(ar - T_) * DIM_ + k0 + csrc * 8);
      } else {
        asrc = A + (size_t)ar * lda + k0 + csrc * 8;
      }
      gload_lds16(asrc, (char*)As + it * 4096 + t * 16);
      const unsigned short* bsrc = B + (size_t)(col0 + r) * ldb + k0 + csrc * 8;
      gload_lds16(bsrc, (char*)Bs + it * 4096 + t * 16);
    }
    __syncthreads();

    short8 af[4], bfv[4];
#pragma unroll
    for (int m = 0; m < 4; ++m) {
      int r = wr * 64 + m * 16 + lr;
      af[m] = *(const short8*)((const char*)As + r * 64 + ((lcg ^ sel) << 4));
    }
#pragma unroll
    for (int n = 0; n < 4; ++n) {
      int r = wc * 64 + n * 16 + lr;
      bfv[n] = *(const short8*)((const char*)Bs + r * 64 + ((lcg ^ sel) << 4));
    }
#pragma unroll
    for (int m = 0; m < 4; ++m)
#pragma unroll
      for (int n = 0; n < 4; ++n)
        acc[m][n] = __builtin_amdgcn_mfma_f32_16x16x32_bf16(af[m], bfv[n], acc[m][n], 0, 0, 0);
    __syncthreads();
  }

#pragma unroll
  for (int m = 0; m < 4; ++m) {
    const int rbase = row0 + wr * 64 + m * 16 + lcg * 4;
#pragma unroll
    for (int n = 0; n < 4; ++n) {
      const int c = col0 + wc * 64 + n * 16 + lr;
      const float bi = bias ? bias[c] : 0.f;
#pragma unroll
      for (int reg = 0; reg < 4; ++reg) {
        const int r = rbase + reg;
        if (r >= M) continue;
        const float v = acc[m][n][reg] + bi;
        if constexpr (OUTMODE == 0) {
          ((float*)Cout)[(size_t)r * N + c] = v;
        } else if constexpr (OUTMODE == 1) {
          ((unsigned short*)Cout)[(size_t)r * N + c] = f2b(v);
        } else if constexpr (OUTMODE == 2) {
          const size_t orow = (r >= T_) ? (size_t)(r - T_) : (size_t)(SV_ + r);
          ((float*)Cout)[orow * N + c] = v;
        } else {
          const int buf = c / DIM_, cc = c - buf * DIM_;
          ((unsigned short*)Cout)[(size_t)buf * S_ * DIM_ + (size_t)r * DIM_ + cc] = f2b(v);
        }
      }
    }
  }
}

// ============================================================================
// MFMA flash attention, swapped QK^T + in-register softmax/P (exp2 domain).
// Block: 4 waves x 16 q-rows; KV tiles of 64. Q pre-scaled by log2(e)/8.
// Lane owns q = q0 + w*16 + (l&15); holds 16 key-scores per tile.
// ============================================================================
__global__ __launch_bounds__(256) void attn_mfma(
    const unsigned short* __restrict__ Qbb,
    const unsigned short* __restrict__ Kbb,
    const unsigned short* __restrict__ Vbb,
    unsigned short* __restrict__ O)
{
  __shared__ __align__(16) unsigned short Kl[64 * 64];   // [key][d], swz 16B
  __shared__ __align__(16) unsigned short Vt[64 * 64];   // [d][key], swz 8-elt

  const int qb = blockIdx.x, h = blockIdx.y;
  const int t = threadIdx.x, w = t >> 6, l = t & 63;
  const int lr = l & 15, lg = l >> 4;
  const int q0 = qb * 64;

  short8 qa[2];
  {
    int qrow = q0 + w * 16 + lr; if (qrow >= S_) qrow = S_ - 1;
    const unsigned short* qp = Qbb + (size_t)qrow * DIM_ + h * 64 + lg * 8;
    qa[0] = *(const short8*)qp;
    qa[1] = *(const short8*)(qp + 32);
  }

  f32x4 oacc[4];
#pragma unroll
  for (int n = 0; n < 4; ++n) oacc[n] = (f32x4){0.f, 0.f, 0.f, 0.f};
  float m_run = -1e30f, l_run = 0.f;

  const int addrA = (lr + ((lg & 1) << 5)) << 2;   // bpermute src lane*4
  const bool hi_m = (lg & 2) != 0;                 // selects c[2ks+1]

  const int NT = (S_ + 63) / 64;
  for (int jt = 0; jt < NT; ++jt) {
    const int j0 = jt * 64;
    __syncthreads();
    // ---- stage K tile (linear LDS dest, pre-swizzled global source) ----
#pragma unroll
    for (int it = 0; it < 2; ++it) {
      const int row = (t >> 3) + it * 32;
      int key = j0 + row; if (key >= S_) key = S_ - 1;
      const int cofs = (((t & 7) * 16) ^ ((row & 7) << 4)) >> 1;
      gload_lds16(Kbb + (size_t)key * DIM_ + h * 64 + cofs,
                  (char*)Kl + it * 4096 + t * 16);
    }
    // ---- stage V transposed: wave w owns dims w*16..+15, key = l ----
    {
      int key = j0 + l; if (key >= S_) key = S_ - 1;
      const unsigned short* vp = Vbb + (size_t)key * DIM_ + h * 64 + w * 16;
      short8 v0 = *(const short8*)vp;
      short8 v1 = *(const short8*)(vp + 8);
#pragma unroll
      for (int i = 0; i < 8; ++i)
        Vt[(w * 16 + i) * 64 + (l ^ ((i & 7) << 3))] = (unsigned short)v0[i];
#pragma unroll
      for (int i = 8; i < 16; ++i)
        Vt[(w * 16 + i) * 64 + (l ^ ((i & 7) << 3))] = (unsigned short)v1[i - 8];
    }
    __syncthreads();

    // ---- S^T = K @ Q^T : lane holds S[key = m*16+lg*4+r][q = lr] ----
    f32x4 sacc[4];
#pragma unroll
    for (int m = 0; m < 4; ++m) sacc[m] = (f32x4){0.f, 0.f, 0.f, 0.f};
    __builtin_amdgcn_s_setprio(1);
#pragma unroll
    for (int m = 0; m < 4; ++m) {
#pragma unroll
      for (int ks = 0; ks < 2; ++ks) {
        const short8 kb = *(const short8*)((const char*)Kl + (m * 16 + lr) * 128 +
                              ((ks * 64 + lg * 16) ^ ((lr & 7) << 4)));
        sacc[m] = __builtin_amdgcn_mfma_f32_16x16x32_bf16(kb, qa[ks], sacc[m], 0, 0, 0);
      }
    }
    __builtin_amdgcn_s_setprio(0);
    if (j0 + 64 > S_) {
#pragma unroll
      for (int m = 0; m < 4; ++m)
#pragma unroll
        for (int r = 0; r < 4; ++r)
          if (j0 + m * 16 + lg * 4 + r >= S_) sacc[m][r] = -1e30f;
    }

    // ---- row max: 15 in-lane + 2 shuffles ----
    float mx = sacc[0][0];
#pragma unroll
    for (int m = 0; m < 4; ++m)
#pragma unroll
      for (int r = 0; r < 4; ++r) mx = fmaxf(mx, sacc[m][r]);
    mx = fmaxf(mx, __shfl_xor(mx, 16));
    mx = fmaxf(mx, __shfl_xor(mx, 32));

    // ---- defer-max rescale (exp2 domain, THR=8) ----
    if (!__all(mx <= m_run + 8.0f)) {
      const float mnew = fmaxf(m_run, mx);
      const float sc = exp2f(m_run - mnew);
      l_run *= sc;
      float scr[4];
#pragma unroll
      for (int r = 0; r < 4; ++r) scr[r] = __shfl(sc, (l & 48) | (lg * 4 + r));
#pragma unroll
      for (int n = 0; n < 4; ++n)
#pragma unroll
        for (int r = 0; r < 4; ++r) oacc[n][r] *= scr[r];
      m_run = mnew;
    }

    // ---- P = exp2(S - m), packed to bf16 pairs in-register ----
    float rs = 0.f;
    int c[4][2];
#pragma unroll
    for (int m = 0; m < 4; ++m) {
      const float p0 = exp2f(sacc[m][0] - m_run);
      const float p1 = exp2f(sacc[m][1] - m_run);
      const float p2 = exp2f(sacc[m][2] - m_run);
      const float p3 = exp2f(sacc[m][3] - m_run);
      rs += (p0 + p1) + (p2 + p3);
      asm("v_cvt_pk_bf16_f32 %0, %1, %2" : "=v"(c[m][0]) : "v"(p0), "v"(p1));
      asm("v_cvt_pk_bf16_f32 %0, %1, %2" : "=v"(c[m][1]) : "v"(p2), "v"(p3));
    }
    rs += __shfl_xor(rs, 16);
    rs += __shfl_xor(rs, 32);
    l_run += rs;

    // ---- build P A-frags via bpermute exchange, then O += P @ V ----
    __builtin_amdgcn_s_setprio(1);
#pragma unroll
    for (int ks = 0; ks < 2; ++ks) {
      const int a0 = __builtin_amdgcn_ds_bpermute(addrA,      c[2 * ks][0]);
      const int b0 = __builtin_amdgcn_ds_bpermute(addrA,      c[2 * ks + 1][0]);
      const int a1 = __builtin_amdgcn_ds_bpermute(addrA,      c[2 * ks][1]);
      const int b1 = __builtin_amdgcn_ds_bpermute(addrA,      c[2 * ks + 1][1]);
      const int a2 = __builtin_amdgcn_ds_bpermute(addrA + 64, c[2 * ks][0]);
      const int b2 = __builtin_amdgcn_ds_bpermute(addrA + 64, c[2 * ks + 1][0]);
      const int a3 = __builtin_amdgcn_ds_bpermute(addrA + 64, c[2 * ks][1]);
      const int b3 = __builtin_amdgcn_ds_bpermute(addrA + 64, c[2 * ks + 1][1]);
      i32x4v pw;
      pw[0] = hi_m ? b0 : a0;
      pw[1] = hi_m ? b1 : a1;
      pw[2] = hi_m ? b2 : a2;
      pw[3] = hi_m ? b3 : a3;
      const short8 pa = __builtin_bit_cast(short8, pw);
#pragma unroll
      for (int n = 0; n < 4; ++n) {
        const short8 vb = *(const short8*)((const char*)Vt + (n * 16 + lr) * 128 +
                              ((ks * 64 + lg * 16) ^ ((lr & 7) << 4)));
        oacc[n] = __builtin_amdgcn_mfma_f32_16x16x32_bf16(pa, vb, oacc[n], 0, 0, 0);
      }
    }
    __builtin_amdgcn_s_setprio(0);
  }

  // ---- epilogue ----
  const float invl = 1.f / l_run;
  float ir[4];
#pragma unroll
  for (int r = 0; r < 4; ++r) ir[r] = __shfl(invl, (l & 48) | (lg * 4 + r));
#pragma unroll
  for (int r = 0; r < 4; ++r) {
    const int row = q0 + w * 16 + lg * 4 + r;
    if (row >= S_) continue;
#pragma unroll
    for (int n = 0; n < 4; ++n)
      O[(size_t)row * DIM_ + h * 64 + n * 16 + lr] = f2b(oacc[n][r] * ir[r]);
  }
}

// ============================================================================
// small kernels
// ============================================================================
__global__ void cvt_w(const float* __restrict__ src, unsigned short* __restrict__ dst, int n)
{
  int i = blockIdx.x * 256 + threadIdx.x;
  if (i < n) dst[i] = f2b(src[i]);
}

__global__ void hidpad_k(const float* __restrict__ hid, unsigned short* __restrict__ dst)
{
  int i = blockIdx.x * 256 + threadIdx.x;
  if (i >= 2560 * DIM_) return;
  int r = i / DIM_;
  dst[i] = (r >= 256 && r < 256 + SV_) ? f2b(hid[i - 256 * DIM_]) : 0;
}

__global__ void encb_k(const float* __restrict__ enc, unsigned short* __restrict__ dst)
{
  int i = blockIdx.x * 256 + threadIdx.x;
  if (i < T_ * DIM_) dst[i] = f2b(enc[i]);
}

__global__ void w1p_k(const float* __restrict__ src, unsigned short* __restrict__ dst)
{
  int i = blockIdx.x * 256 + threadIdx.x;           // over 128*5760
  if (i >= RANK_ * DIM_ * 3) return;
  int oc = i / (DIM_ * 3), rem = i % (DIM_ * 3);
  int ks = rem / DIM_, ic = rem % DIM_;
  dst[i] = f2b(src[(size_t)oc * DIM_ * 3 + ic * 3 + ks]);
}

__global__ void w2p_k(const float* __restrict__ src, unsigned short* __restrict__ dst)
{
  int i = blockIdx.x * 256 + threadIdx.x;           // over 1920*384
  if (i >= DIM_ * RANK_ * 3) return;
  int oc = i / (RANK_ * 3), rem = i % (RANK_ * 3);
  int ks = rem / RANK_, rc = rem % RANK_;
  dst[i] = f2b(src[(size_t)oc * RANK_ * 3 + rc * 3 + ks]);
}

__global__ void wqkv_k(const float* __restrict__ q, const float* __restrict__ k,
                       const float* __restrict__ v, unsigned short* __restrict__ dst)
{
  int i = blockIdx.x * 256 + threadIdx.x;           // over 3*DIM*DIM
  if (i >= 3 * DIM_ * DIM_) return;
  int which = i / (DIM_ * DIM_), j = i % (DIM_ * DIM_);
  const float* s = which == 0 ? q : which == 1 ? k : v;
  dst[i] = f2b(s[j]);
}

__global__ void bqkv_k(const float* __restrict__ q, const float* __restrict__ k,
                       const float* __restrict__ v, float* __restrict__ dst)
{
  int i = blockIdx.x * 256 + threadIdx.x;           // over 3*DIM
  if (i >= 3 * DIM_) return;
  int which = i / DIM_, j = i % DIM_;
  dst[i] = which == 0 ? q[j] : which == 1 ? k[j] : v[j];
}

// sum 12 split-K partials of y1^T [128][2048], GELU, write padded [2560][128]
__global__ void gelupad_k(const float* __restrict__ y1T, unsigned short* __restrict__ dst)
{
  int i = blockIdx.x * 256 + threadIdx.x;           // over 2560*128
  if (i >= 2560 * RANK_) return;
  int r = i / RANK_, rc = i % RANK_;
  unsigned short o = 0;
  if (r >= 256 && r < 256 + SV_) {
    int s = r - 256;
    float x = 0.f;
#pragma unroll
    for (int z = 0; z < 12; ++z)
      x += y1T[(size_t)z * RANK_ * SV_ + (size_t)rc * SV_ + s];
    o = f2b(0.5f * x * (1.f + erff(x * 0.70710678118654752f)));
  }
  dst[i] = o;
}

__global__ void addcvt_k(const unsigned short* __restrict__ Ob,
                         const unsigned short* __restrict__ y2b,
                         unsigned short* __restrict__ attnb)
{
  int i = blockIdx.x * 256 + threadIdx.x;           // over S_*DIM_
  if (i >= S_ * DIM_) return;
  int r = i / DIM_;
  float v = b2f(Ob[i]);
  if (r >= T_) v += b2f(y2b[i - T_ * DIM_]);
  attnb[i] = f2b(v);
}

// LN over HD=64 + RoPE, bf16 in place; Q branch scaled by log2(e)/8
__global__ __launch_bounds__(256) void qknorm_rope(
    unsigned short* __restrict__ Qbb, unsigned short* __restrict__ Kbb,
    const float* __restrict__ nq_w, const float* __restrict__ nq_b,
    const float* __restrict__ nk_w, const float* __restrict__ nk_b,
    const float* __restrict__ cosT, const float* __restrict__ sinT)
{
  const int w = threadIdx.x >> 6, lane = threadIdx.x & 63;
  const int idx = blockIdx.x * 4 + w;
  if (idx >= S_ * HEADS_) return;
  const int s = idx / HEADS_, h = idx % HEADS_;
  unsigned short* X = blockIdx.y ? Kbb : Qbb;
  const float* wt = blockIdx.y ? nk_w : nq_w;
  const float* bt = blockIdx.y ? nk_b : nq_b;
  const size_t off = (size_t)s * DIM_ + h * HD_ + lane;
  float x = b2f(X[off]);
  float m = x;
#pragma unroll
  for (int o = 32; o; o >>= 1) m += __shfl_xor(m, o);
  m *= (1.f / 64.f);
  float d = x - m;
  float v = d * d;
#pragma unroll
  for (int o = 32; o; o >>= 1) v += __shfl_xor(v, o);
  v *= (1.f / 64.f);
  float y = d * rsqrtf(v + 1e-6f) * wt[lane] + bt[lane];
  if (s >= T_) {
    float p = __shfl_xor(y, 1);
    float rot = (lane & 1) ? p : -p;
    int sv = s - T_;
    y = y * cosT[(size_t)sv * HD_ + lane] + rot * sinT[(size_t)sv * HD_ + lane];
  }
  if (!blockIdx.y) y *= 0.18033688011112042f;   // (1/8) * log2(e)
  X[off] = f2b(y);
}

// ============================================================================
extern "C" void kernel_launch(void* const* d_in, const int* in_sizes, int n_in,
                              void* d_out, int out_size, void* d_ws, size_t ws_size,
                              hipStream_t stream)
{
  const float* hidden  = (const float*)d_in[0];
  const float* encoder = (const float*)d_in[1];
  const float* cosT    = (const float*)d_in[2];
  const float* sinT    = (const float*)d_in[3];
  const float* to_q_w  = (const float*)d_in[4];
  const float* to_q_b  = (const float*)d_in[5];
  const float* to_k_w  = (const float*)d_in[6];
  const float* to_k_b  = (const float*)d_in[7];
  const float* to_v_w  = (const float*)d_in[8];
  const float* to_v_b  = (const float*)d_in[9];
  const float* nq_w    = (const float*)d_in[10];
  const float* nq_b    = (const float*)d_in[11];
  const float* nk_w    = (const float*)d_in[12];
  const float* nk_b    = (const float*)d_in[13];
  const float* conv1_w = (const float*)d_in[14];
  const float* conv2_w = (const float*)d_in[15];
  const float* to_out_w = (const float*)d_in[16];
  const float* to_out_b = (const float*)d_in[17];
  float* out = (float*)d_out;

  // ---- workspace layout (~80.1 MB; >=85.59 MB proven available) ----
  char* p = (char*)d_ws;
  unsigned short* hidpad = (unsigned short*)p;  p += (size_t)2560 * DIM_ * 2;        // 9.83 MB
  unsigned short* y2b    = (unsigned short*)p;  p += (size_t)SV_ * DIM_ * 2;         // 7.86 MB
  unsigned short* wqkv   = (unsigned short*)p;  p += (size_t)3 * DIM_ * DIM_ * 2;    // 22.1 MB
  unsigned short* QKVbb  = (unsigned short*)p;  p += (size_t)3 * S_ * DIM_ * 2;      // 26.2 MB
  unsigned short* encb   = (unsigned short*)p;  p += (size_t)T_ * DIM_ * 2;          // 0.87 MB
  float*          y1T    = (float*)p;           p += (size_t)12 * RANK_ * SV_ * 4;   // 12.6 MB
  unsigned short* gelup  = (unsigned short*)p;  p += (size_t)2560 * RANK_ * 2;       // 0.66 MB
  float*          bqkv   = (float*)p;           p += (size_t)3 * DIM_ * 4;           // 23 KB
  unsigned short* Qbb = QKVbb;
  unsigned short* Kbb = QKVbb + (size_t)S_ * DIM_;
  unsigned short* Vbb = QKVbb + (size_t)2 * S_ * DIM_;
  unsigned short* attnb = Kbb;                  // post-attn reuse

  // ---- input conversions ----
  hidpad_k<<<(2560 * DIM_ + 255) / 256, 256, 0, stream>>>(hidden, hidpad);
  encb_k<<<(T_ * DIM_ + 255) / 256, 256, 0, stream>>>(encoder, encb);

  // ---- conv branch ----
  w1p_k<<<(RANK_ * DIM_ * 3 + 255) / 256, 256, 0, stream>>>(conv1_w, wqkv);
  gemm_mfma<3, 0><<<dim3(SV_ / BN, 1, 12), 256, 0, stream>>>(
      wqkv, nullptr, hidpad, nullptr, y1T, RANK_, SV_, 480, DIM_ * 3, DIM_, 1);
  gelupad_k<<<(2560 * RANK_ + 255) / 256, 256, 0, stream>>>(y1T, gelup);
  w2p_k<<<(DIM_ * RANK_ * 3 + 255) / 256, 256, 0, stream>>>(conv2_w, wqkv);
  gemm_mfma<1, 1><<<dim3(DIM_ / BN, SV_ / BM), 256, 0, stream>>>(
      gelup, nullptr, wqkv, nullptr, y2b, SV_, DIM_, RANK_ * 3, RANK_ * 3, RANK_ * 3, RANK_);

  // ---- fused QKV projection (bf16 out) ----
  wqkv_k<<<(3 * DIM_ * DIM_ + 255) / 256, 256, 0, stream>>>(to_q_w, to_k_w, to_v_w, wqkv);
  bqkv_k<<<(3 * DIM_ + 255) / 256, 256, 0, stream>>>(to_q_b, to_k_b, to_v_b, bqkv);
  const unsigned short* hid0 = hidpad + (size_t)256 * DIM_;
  gemm_mfma<2, 3><<<dim3(3 * DIM_ / BN, (S_ + BM - 1) / BM), 256, 0, stream>>>(
      encb, hid0, wqkv, bqkv, QKVbb, S_, 3 * DIM_, DIM_, DIM_, DIM_, 1);

  // ---- LN + RoPE (bf16 in place; Q scaled log2e/8) ----
  qknorm_rope<<<dim3((S_ * HEADS_ + 3) / 4, 2), 256, 0, stream>>>(
      Qbb, Kbb, nq_w, nq_b, nk_w, nk_b, cosT, sinT);

  // ---- MFMA flash attention (O bf16 over Qbb) ----
  attn_mfma<<<dim3((S_ + 63) / 64, HEADS_), 256, 0, stream>>>(Qbb, Kbb, Vbb, Qbb);

  // ---- add conv branch (bf16) ----
  addcvt_k<<<(S_ * DIM_ + 255) / 256, 256, 0, stream>>>(Qbb, y2b, attnb);

  // ---- output projection -> d_out (fp32, tuple remap) ----
  cvt_w<<<(DIM_ * DIM_ + 255) / 256, 256, 0, stream>>>(to_out_w, wqkv, DIM_ * DIM_);
  gemm_mfma<0, 2><<<dim3(DIM_ / BN, (S_ + BM - 1) / BM), 256, 0, stream>>>(
      attnb, nullptr, wqkv, to_out_b, out, S_, DIM_, DIM_, DIM_, DIM_, 1);
}

// Round 5
// 442.837 us; speedup vs baseline: 10.9680x; 1.0372x over previous
//
#include <hip/hip_runtime.h>
#include <hip/hip_bf16.h>
#include <math.h>

#define F_     8
#define DIM_   1920
#define HEADS_ 30
#define HD_    64
#define RANK_  128
#define T_     226
#define SV_    2048
#define S_     2274

#define BM 128
#define BN 128
#define BK 32

using short8 = __attribute__((ext_vector_type(8))) short;
using f32x4  = __attribute__((ext_vector_type(4))) float;
using i32x4v = __attribute__((ext_vector_type(4))) int;

__device__ __forceinline__ unsigned short f2b(float f) {
  unsigned int u = __float_as_uint(f);
  u = (u + 0x7FFFu + ((u >> 16) & 1u)) >> 16;
  return (unsigned short)u;
}
__device__ __forceinline__ float b2f(unsigned short s) {
  return __uint_as_float(((unsigned int)s) << 16);
}
__device__ __forceinline__ void gload_lds16(const void* g, void* l) {
  __builtin_amdgcn_global_load_lds(
      (const __attribute__((address_space(1))) unsigned int*)g,
      (__attribute__((address_space(3))) unsigned int*)l, 16, 0, 0);
}
// bijective XCD-aware swizzle (m204): consecutive remapped ids stay on one XCD
__device__ __forceinline__ void xcd_swz(int& bx, int& by) {
  const int nx = gridDim.x;
  const int nwg = nx * gridDim.y;
  const int lid = by * nx + bx;
  const int q = nwg >> 3, r = nwg & 7;
  const int xcd = lid & 7, pos = lid >> 3;
  const int wg = (xcd < r ? xcd * (q + 1) : r * (q + 1) + (xcd - r) * q) + pos;
  bx = wg % nx; by = wg / nx;
}

// ============================================================================
// MFMA bf16 GEMM:  C(MxN) = A(MxK) @ B(NxK)^T [+ bias]
// AMODE 0: A plain row-major, stride lda
// AMODE 1: conv shifts: col kk -> A[r + (kk/kinner)*256][kk%kinner]
// AMODE 2: concat rows: r<T_ -> A, else A2+(r-T_); lda=DIM_
// AMODE 3: conv1 split-K x12: z: A+=z*480 (1920=4*480), B row += (z>>2)*256,
//          B col += (z&3)*480, Cout partial z. Launch with K=480.
// OUTMODE 0: f32  1: bf16  2: f32 tuple-remap  3: bf16 QKV col-split
// ============================================================================
template<int AMODE, int OUTMODE>
__global__ __launch_bounds__(256) void gemm_mfma(
    const unsigned short* __restrict__ A,
    const unsigned short* __restrict__ A2,
    const unsigned short* __restrict__ B,
    const float* __restrict__ bias,
    void* __restrict__ Cout,
    int M, int N, int K, int lda, int ldb, int kinner)
{
  __shared__ __align__(16) unsigned short As[BM * BK];
  __shared__ __align__(16) unsigned short Bs[BN * BK];
  if constexpr (AMODE == 3) {
    const int z = blockIdx.z;
    A += (size_t)z * 480;
    B += (size_t)(z >> 2) * 256 * DIM_ + (z & 3) * 480;
    Cout = (void*)((float*)Cout + (size_t)z * M * N);
  }
  int bx = blockIdx.x, by = blockIdx.y;
  xcd_swz(bx, by);
  const int t   = threadIdx.x;
  const int w   = t >> 6, l = t & 63;
  const int wr  = w >> 1, wc = w & 1;
  const int row0 = by * BM, col0 = bx * BN;
  const int lr  = l & 15;
  const int lcg = l >> 4;
  const int sel = (lr >> 1) & 3;
  const int sr  = t >> 2;
  const int sc  = t & 3;

  f32x4 acc[4][4];
#pragma unroll
  for (int i = 0; i < 4; ++i)
#pragma unroll
    for (int j = 0; j < 4; ++j) acc[i][j] = (f32x4){0.f, 0.f, 0.f, 0.f};

  for (int k0 = 0; k0 < K; k0 += BK) {
    int kseg = 0, kcol = k0;
    if constexpr (AMODE == 1) { kseg = k0 / kinner; kcol = k0 - kseg * kinner; }
#pragma unroll
    for (int it = 0; it < 2; ++it) {
      const int r    = it * 64 + sr;
      const int csrc = sc ^ ((r >> 1) & 3);
      int ar = row0 + r; if (ar > M - 1) ar = M - 1;
      const unsigned short* asrc;
      if constexpr (AMODE == 1) {
        asrc = A + (size_t)(ar + kseg * 256) * kinner + kcol + csrc * 8;
      } else if constexpr (AMODE == 2) {
        asrc = (ar < T_) ? (A  + (size_t)ar        * DIM_ + k0 + csrc * 8)
                         : (A2 + (size_t)(ar - T_) * DIM_ + k0 + csrc * 8);
      } else {
        asrc = A + (size_t)ar * lda + k0 + csrc * 8;
      }
      gload_lds16(asrc, (char*)As + it * 4096 + t * 16);
      const unsigned short* bsrc = B + (size_t)(col0 + r) * ldb + k0 + csrc * 8;
      gload_lds16(bsrc, (char*)Bs + it * 4096 + t * 16);
    }
    __syncthreads();

    short8 af[4], bfv[4];
#pragma unroll
    for (int m = 0; m < 4; ++m) {
      int r = wr * 64 + m * 16 + lr;
      af[m] = *(const short8*)((const char*)As + r * 64 + ((lcg ^ sel) << 4));
    }
#pragma unroll
    for (int n = 0; n < 4; ++n) {
      int r = wc * 64 + n * 16 + lr;
      bfv[n] = *(const short8*)((const char*)Bs + r * 64 + ((lcg ^ sel) << 4));
    }
    __builtin_amdgcn_s_setprio(1);
#pragma unroll
    for (int m = 0; m < 4; ++m)
#pragma unroll
      for (int n = 0; n < 4; ++n)
        acc[m][n] = __builtin_amdgcn_mfma_f32_16x16x32_bf16(af[m], bfv[n], acc[m][n], 0, 0, 0);
    __builtin_amdgcn_s_setprio(0);
    __syncthreads();
  }

#pragma unroll
  for (int m = 0; m < 4; ++m) {
    const int rbase = row0 + wr * 64 + m * 16 + lcg * 4;
#pragma unroll
    for (int n = 0; n < 4; ++n) {
      const int c = col0 + wc * 64 + n * 16 + lr;
      const float bi = bias ? bias[c] : 0.f;
#pragma unroll
      for (int reg = 0; reg < 4; ++reg) {
        const int r = rbase + reg;
        if (r >= M) continue;
        const float v = acc[m][n][reg] + bi;
        if constexpr (OUTMODE == 0) {
          ((float*)Cout)[(size_t)r * N + c] = v;
        } else if constexpr (OUTMODE == 1) {
          ((unsigned short*)Cout)[(size_t)r * N + c] = f2b(v);
        } else if constexpr (OUTMODE == 2) {
          const size_t orow = (r >= T_) ? (size_t)(r - T_) : (size_t)(SV_ + r);
          ((float*)Cout)[orow * N + c] = v;
        } else {
          const int buf = c / DIM_, cc = c - buf * DIM_;
          ((unsigned short*)Cout)[(size_t)buf * S_ * DIM_ + (size_t)r * DIM_ + cc] = f2b(v);
        }
      }
    }
  }
}

// ============================================================================
// MFMA flash attention, swapped QK^T + in-register softmax/P (exp2 domain).
// Double-buffered async staging: K via global_load_lds, V via reg-stage
// (issue-early / ds_write-late, T14). One barrier per KV tile.
// Conv-branch add fused into the epilogue (rows >= T_).
// ============================================================================
__global__ __launch_bounds__(256) void attn_mfma(
    const unsigned short* __restrict__ Qbb,
    const unsigned short* __restrict__ Kbb,
    const unsigned short* __restrict__ Vbb,
    const unsigned short* __restrict__ y2b,
    unsigned short* __restrict__ O)
{
  __shared__ __align__(16) unsigned short Kl[2][64 * 64];   // [key][d], swz 16B
  __shared__ __align__(16) unsigned short Vt[2][64 * 64];   // [d][key], swz 8-elt

  int bx = blockIdx.x, by = blockIdx.y;
  xcd_swz(bx, by);                       // groups same-head q-blocks per XCD
  const int qb = bx, h = by;
  const int t = threadIdx.x, w = t >> 6, l = t & 63;
  const int lr = l & 15, lg = l >> 4;
  const int q0 = qb * 64;

  short8 qa[2];
  {
    int qrow = q0 + w * 16 + lr; if (qrow >= S_) qrow = S_ - 1;
    const unsigned short* qp = Qbb + (size_t)qrow * DIM_ + h * 64 + lg * 8;
    qa[0] = *(const short8*)qp;
    qa[1] = *(const short8*)(qp + 32);
  }

  // staging address pieces (constant per thread)
  const int krow0 = t >> 3;              // K-stage row, it=0 (+32 for it=1)
  const int kc0 = ((((t & 7) * 16) ^ ((krow0        & 7) << 4)) >> 1);
  const int kc1 = ((((t & 7) * 16) ^ (((krow0 + 32) & 7) << 4)) >> 1);

  f32x4 oacc[4];
#pragma unroll
  for (int n = 0; n < 4; ++n) oacc[n] = (f32x4){0.f, 0.f, 0.f, 0.f};
  float m_run = -1e30f, l_run = 0.f;

  const int addrA = (lr + ((lg & 1) << 5)) << 2;   // bpermute src lane*4
  const bool hi_m = (lg & 2) != 0;                 // selects c[2ks+1]

  const int NT = (S_ + 63) / 64;

  // ---- prologue: stage tile 0 ----
  {
    int k0 = 0 + krow0;      if (k0 >= S_) k0 = S_ - 1;
    int k1 = 0 + krow0 + 32; if (k1 >= S_) k1 = S_ - 1;
    gload_lds16(Kbb + (size_t)k0 * DIM_ + h * 64 + kc0, (char*)Kl[0] + t * 16);
    gload_lds16(Kbb + (size_t)k1 * DIM_ + h * 64 + kc1, (char*)Kl[0] + 4096 + t * 16);
    int key = l; if (key >= S_) key = S_ - 1;
    const unsigned short* vp = Vbb + (size_t)key * DIM_ + h * 64 + w * 16;
    short8 v0 = *(const short8*)vp;
    short8 v1 = *(const short8*)(vp + 8);
#pragma unroll
    for (int i = 0; i < 8; ++i)
      Vt[0][(w * 16 + i) * 64 + (l ^ ((i & 7) << 3))] = (unsigned short)v0[i];
#pragma unroll
    for (int i = 8; i < 16; ++i)
      Vt[0][(w * 16 + i) * 64 + (l ^ ((i & 7) << 3))] = (unsigned short)v1[i - 8];
  }
  __syncthreads();

  for (int jt = 0; jt < NT; ++jt) {
    const int j0 = jt * 64;
    const int cur = jt & 1;

    // ---- issue prefetch for tile jt+1 (clamped re-read on last iter) ----
    const int jn0 = (jt + 1 < NT) ? (jt + 1) * 64 : jt * 64;
    {
      int k0 = jn0 + krow0;      if (k0 >= S_) k0 = S_ - 1;
      int k1 = jn0 + krow0 + 32; if (k1 >= S_) k1 = S_ - 1;
      gload_lds16(Kbb + (size_t)k0 * DIM_ + h * 64 + kc0,
                  (char*)Kl[cur ^ 1] + t * 16);
      gload_lds16(Kbb + (size_t)k1 * DIM_ + h * 64 + kc1,
                  (char*)Kl[cur ^ 1] + 4096 + t * 16);
    }
    short8 nv0, nv1;
    {
      int key = jn0 + l; if (key >= S_) key = S_ - 1;
      const unsigned short* vp = Vbb + (size_t)key * DIM_ + h * 64 + w * 16;
      nv0 = *(const short8*)vp;
      nv1 = *(const short8*)(vp + 8);
    }

    // ---- S^T = K @ Q^T : lane holds S[key = m*16+lg*4+r][q = lr] ----
    f32x4 sacc[4];
#pragma unroll
    for (int m = 0; m < 4; ++m) sacc[m] = (f32x4){0.f, 0.f, 0.f, 0.f};
    __builtin_amdgcn_s_setprio(1);
#pragma unroll
    for (int m = 0; m < 4; ++m) {
#pragma unroll
      for (int ks = 0; ks < 2; ++ks) {
        const short8 kb = *(const short8*)((const char*)Kl[cur] + (m * 16 + lr) * 128 +
                              ((ks * 64 + lg * 16) ^ ((lr & 7) << 4)));
        sacc[m] = __builtin_amdgcn_mfma_f32_16x16x32_bf16(kb, qa[ks], sacc[m], 0, 0, 0);
      }
    }
    __builtin_amdgcn_s_setprio(0);
    if (j0 + 64 > S_) {
#pragma unroll
      for (int m = 0; m < 4; ++m)
#pragma unroll
        for (int r = 0; r < 4; ++r)
          if (j0 + m * 16 + lg * 4 + r >= S_) sacc[m][r] = -1e30f;
    }

    // ---- row max: 15 in-lane + 2 shuffles ----
    float mx = sacc[0][0];
#pragma unroll
    for (int m = 0; m < 4; ++m)
#pragma unroll
      for (int r = 0; r < 4; ++r) mx = fmaxf(mx, sacc[m][r]);
    mx = fmaxf(mx, __shfl_xor(mx, 16));
    mx = fmaxf(mx, __shfl_xor(mx, 32));

    // ---- defer-max rescale (exp2 domain, THR=8) ----
    if (!__all(mx <= m_run + 8.0f)) {
      const float mnew = fmaxf(m_run, mx);
      const float sc = exp2f(m_run - mnew);
      l_run *= sc;
      float scr[4];
#pragma unroll
      for (int r = 0; r < 4; ++r) scr[r] = __shfl(sc, (l & 48) | (lg * 4 + r));
#pragma unroll
      for (int n = 0; n < 4; ++n)
#pragma unroll
        for (int r = 0; r < 4; ++r) oacc[n][r] *= scr[r];
      m_run = mnew;
    }

    // ---- P = exp2(S - m), packed to bf16 pairs in-register ----
    float rs = 0.f;
    int c[4][2];
#pragma unroll
    for (int m = 0; m < 4; ++m) {
      const float p0 = exp2f(sacc[m][0] - m_run);
      const float p1 = exp2f(sacc[m][1] - m_run);
      const float p2 = exp2f(sacc[m][2] - m_run);
      const float p3 = exp2f(sacc[m][3] - m_run);
      rs += (p0 + p1) + (p2 + p3);
      asm("v_cvt_pk_bf16_f32 %0, %1, %2" : "=v"(c[m][0]) : "v"(p0), "v"(p1));
      asm("v_cvt_pk_bf16_f32 %0, %1, %2" : "=v"(c[m][1]) : "v"(p2), "v"(p3));
    }
    rs += __shfl_xor(rs, 16);
    rs += __shfl_xor(rs, 32);
    l_run += rs;

    // ---- build P A-frags via bpermute exchange, then O += P @ V ----
    __builtin_amdgcn_s_setprio(1);
#pragma unroll
    for (int ks = 0; ks < 2; ++ks) {
      const int a0 = __builtin_amdgcn_ds_bpermute(addrA,      c[2 * ks][0]);
      const int b0 = __builtin_amdgcn_ds_bpermute(addrA,      c[2 * ks + 1][0]);
      const int a1 = __builtin_amdgcn_ds_bpermute(addrA,      c[2 * ks][1]);
      const int b1 = __builtin_amdgcn_ds_bpermute(addrA,      c[2 * ks + 1][1]);
      const int a2 = __builtin_amdgcn_ds_bpermute(addrA + 64, c[2 * ks][0]);
      const int b2 = __builtin_amdgcn_ds_bpermute(addrA + 64, c[2 * ks + 1][0]);
      const int a3 = __builtin_amdgcn_ds_bpermute(addrA + 64, c[2 * ks][1]);
      const int b3 = __builtin_amdgcn_ds_bpermute(addrA + 64, c[2 * ks + 1][1]);
      i32x4v pw;
      pw[0] = hi_m ? b0 : a0;
      pw[1] = hi_m ? b1 : a1;
      pw[2] = hi_m ? b2 : a2;
      pw[3] = hi_m ? b3 : a3;
      const short8 pa = __builtin_bit_cast(short8, pw);
#pragma unroll
      for (int n = 0; n < 4; ++n) {
        const short8 vb = *(const short8*)((const char*)Vt[cur] + (n * 16 + lr) * 128 +
                              ((ks * 64 + lg * 16) ^ ((lr & 7) << 4)));
        oacc[n] = __builtin_amdgcn_mfma_f32_16x16x32_bf16(pa, vb, oacc[n], 0, 0, 0);
      }
    }
    __builtin_amdgcn_s_setprio(0);

    // ---- late V write into the other buffer (waits its global loads) ----
#pragma unroll
    for (int i = 0; i < 8; ++i)
      Vt[cur ^ 1][(w * 16 + i) * 64 + (l ^ ((i & 7) << 3))] = (unsigned short)nv0[i];
#pragma unroll
    for (int i = 8; i < 16; ++i)
      Vt[cur ^ 1][(w * 16 + i) * 64 + (l ^ ((i & 7) << 3))] = (unsigned short)nv1[i - 8];
    __syncthreads();     // drains K-DMA (vmcnt) + Vt writes for next iter
  }

  // ---- epilogue: divide by l, add conv branch (rows >= T_), store bf16 ----
  const float invl = 1.f / l_run;
  float ir[4];
#pragma unroll
  for (int r = 0; r < 4; ++r) ir[r] = __shfl(invl, (l & 48) | (lg * 4 + r));
#pragma unroll
  for (int r = 0; r < 4; ++r) {
    const int row = q0 + w * 16 + lg * 4 + r;
    if (row >= S_) continue;
#pragma unroll
    for (int n = 0; n < 4; ++n) {
      const int col = h * 64 + n * 16 + lr;
      float v = oacc[n][r] * ir[r];
      if (row >= T_) v += b2f(y2b[(size_t)(row - T_) * DIM_ + col]);
      O[(size_t)row * DIM_ + col] = f2b(v);
    }
  }
}

// ============================================================================
// small kernels
// ============================================================================
__global__ void cvt_w(const float* __restrict__ src, unsigned short* __restrict__ dst, int n)
{
  int i = blockIdx.x * 256 + threadIdx.x;
  if (i < n) dst[i] = f2b(src[i]);
}

__global__ void hidpad_k(const float* __restrict__ hid, unsigned short* __restrict__ dst)
{
  int i = blockIdx.x * 256 + threadIdx.x;
  if (i >= 2560 * DIM_) return;
  int r = i / DIM_;
  dst[i] = (r >= 256 && r < 256 + SV_) ? f2b(hid[i - 256 * DIM_]) : 0;
}

__global__ void encb_k(const float* __restrict__ enc, unsigned short* __restrict__ dst)
{
  int i = blockIdx.x * 256 + threadIdx.x;
  if (i < T_ * DIM_) dst[i] = f2b(enc[i]);
}

__global__ void w1p_k(const float* __restrict__ src, unsigned short* __restrict__ dst)
{
  int i = blockIdx.x * 256 + threadIdx.x;           // over 128*5760
  if (i >= RANK_ * DIM_ * 3) return;
  int oc = i / (DIM_ * 3), rem = i % (DIM_ * 3);
  int ks = rem / DIM_, ic = rem % DIM_;
  dst[i] = f2b(src[(size_t)oc * DIM_ * 3 + ic * 3 + ks]);
}

__global__ void w2p_k(const float* __restrict__ src, unsigned short* __restrict__ dst)
{
  int i = blockIdx.x * 256 + threadIdx.x;           // over 1920*384
  if (i >= DIM_ * RANK_ * 3) return;
  int oc = i / (RANK_ * 3), rem = i % (RANK_ * 3);
  int ks = rem / RANK_, rc = rem % RANK_;
  dst[i] = f2b(src[(size_t)oc * RANK_ * 3 + rc * 3 + ks]);
}

__global__ void wqkv_k(const float* __restrict__ q, const float* __restrict__ k,
                       const float* __restrict__ v, unsigned short* __restrict__ dst)
{
  int i = blockIdx.x * 256 + threadIdx.x;           // over 3*DIM*DIM
  if (i >= 3 * DIM_ * DIM_) return;
  int which = i / (DIM_ * DIM_), j = i % (DIM_ * DIM_);
  const float* s = which == 0 ? q : which == 1 ? k : v;
  dst[i] = f2b(s[j]);
}

__global__ void bqkv_k(const float* __restrict__ q, const float* __restrict__ k,
                       const float* __restrict__ v, float* __restrict__ dst)
{
  int i = blockIdx.x * 256 + threadIdx.x;           // over 3*DIM
  if (i >= 3 * DIM_) return;
  int which = i / DIM_, j = i % DIM_;
  dst[i] = which == 0 ? q[j] : which == 1 ? k[j] : v[j];
}

// sum 12 split-K partials of y1^T [128][2048], GELU, write padded [2560][128]
__global__ void gelupad_k(const float* __restrict__ y1T, unsigned short* __restrict__ dst)
{
  int i = blockIdx.x * 256 + threadIdx.x;           // over 2560*128
  if (i >= 2560 * RANK_) return;
  int r = i / RANK_, rc = i % RANK_;
  unsigned short o = 0;
  if (r >= 256 && r < 256 + SV_) {
    int s = r - 256;
    float x = 0.f;
#pragma unroll
    for (int z = 0; z < 12; ++z)
      x += y1T[(size_t)z * RANK_ * SV_ + (size_t)rc * SV_ + s];
    o = f2b(0.5f * x * (1.f + erff(x * 0.70710678118654752f)));
  }
  dst[i] = o;
}

// LN over HD=64 + RoPE, bf16 in place; Q branch scaled by log2(e)/8
__global__ __launch_bounds__(256) void qknorm_rope(
    unsigned short* __restrict__ Qbb, unsigned short* __restrict__ Kbb,
    const float* __restrict__ nq_w, const float* __restrict__ nq_b,
    const float* __restrict__ nk_w, const float* __restrict__ nk_b,
    const float* __restrict__ cosT, const float* __restrict__ sinT)
{
  const int w = threadIdx.x >> 6, lane = threadIdx.x & 63;
  const int idx = blockIdx.x * 4 + w;
  if (idx >= S_ * HEADS_) return;
  const int s = idx / HEADS_, h = idx % HEADS_;
  unsigned short* X = blockIdx.y ? Kbb : Qbb;
  const float* wt = blockIdx.y ? nk_w : nq_w;
  const float* bt = blockIdx.y ? nk_b : nq_b;
  const size_t off = (size_t)s * DIM_ + h * HD_ + lane;
  float x = b2f(X[off]);
  float m = x;
#pragma unroll
  for (int o = 32; o; o >>= 1) m += __shfl_xor(m, o);
  m *= (1.f / 64.f);
  float d = x - m;
  float v = d * d;
#pragma unroll
  for (int o = 32; o; o >>= 1) v += __shfl_xor(v, o);
  v *= (1.f / 64.f);
  float y = d * rsqrtf(v + 1e-6f) * wt[lane] + bt[lane];
  if (s >= T_) {
    float p = __shfl_xor(y, 1);
    float rot = (lane & 1) ? p : -p;
    int sv = s - T_;
    y = y * cosT[(size_t)sv * HD_ + lane] + rot * sinT[(size_t)sv * HD_ + lane];
  }
  if (!blockIdx.y) y *= 0.18033688011112042f;   // (1/8) * log2(e)
  X[off] = f2b(y);
}

// ============================================================================
extern "C" void kernel_launch(void* const* d_in, const int* in_sizes, int n_in,
                              void* d_out, int out_size, void* d_ws, size_t ws_size,
                              hipStream_t stream)
{
  const float* hidden  = (const float*)d_in[0];
  const float* encoder = (const float*)d_in[1];
  const float* cosT    = (const float*)d_in[2];
  const float* sinT    = (const float*)d_in[3];
  const float* to_q_w  = (const float*)d_in[4];
  const float* to_q_b  = (const float*)d_in[5];
  const float* to_k_w  = (const float*)d_in[6];
  const float* to_k_b  = (const float*)d_in[7];
  const float* to_v_w  = (const float*)d_in[8];
  const float* to_v_b  = (const float*)d_in[9];
  const float* nq_w    = (const float*)d_in[10];
  const float* nq_b    = (const float*)d_in[11];
  const float* nk_w    = (const float*)d_in[12];
  const float* nk_b    = (const float*)d_in[13];
  const float* conv1_w = (const float*)d_in[14];
  const float* conv2_w = (const float*)d_in[15];
  const float* to_out_w = (const float*)d_in[16];
  const float* to_out_b = (const float*)d_in[17];
  float* out = (float*)d_out;

  // ---- workspace layout (~80.1 MB; >=85.59 MB proven available) ----
  char* p = (char*)d_ws;
  unsigned short* hidpad = (unsigned short*)p;  p += (size_t)2560 * DIM_ * 2;        // 9.83 MB
  unsigned short* y2b    = (unsigned short*)p;  p += (size_t)SV_ * DIM_ * 2;         // 7.86 MB
  unsigned short* wqkv   = (unsigned short*)p;  p += (size_t)3 * DIM_ * DIM_ * 2;    // 22.1 MB
  unsigned short* QKVbb  = (unsigned short*)p;  p += (size_t)3 * S_ * DIM_ * 2;      // 26.2 MB
  unsigned short* encb   = (unsigned short*)p;  p += (size_t)T_ * DIM_ * 2;          // 0.87 MB
  float*          y1T    = (float*)p;           p += (size_t)12 * RANK_ * SV_ * 4;   // 12.6 MB
  unsigned short* gelup  = (unsigned short*)p;  p += (size_t)2560 * RANK_ * 2;       // 0.66 MB
  float*          bqkv   = (float*)p;           p += (size_t)3 * DIM_ * 4;           // 23 KB
  unsigned short* Qbb = QKVbb;
  unsigned short* Kbb = QKVbb + (size_t)S_ * DIM_;
  unsigned short* Vbb = QKVbb + (size_t)2 * S_ * DIM_;

  // ---- input conversions ----
  hidpad_k<<<(2560 * DIM_ + 255) / 256, 256, 0, stream>>>(hidden, hidpad);
  encb_k<<<(T_ * DIM_ + 255) / 256, 256, 0, stream>>>(encoder, encb);

  // ---- conv branch ----
  w1p_k<<<(RANK_ * DIM_ * 3 + 255) / 256, 256, 0, stream>>>(conv1_w, wqkv);
  gemm_mfma<3, 0><<<dim3(SV_ / BN, 1, 12), 256, 0, stream>>>(
      wqkv, nullptr, hidpad, nullptr, y1T, RANK_, SV_, 480, DIM_ * 3, DIM_, 1);
  gelupad_k<<<(2560 * RANK_ + 255) / 256, 256, 0, stream>>>(y1T, gelup);
  w2p_k<<<(DIM_ * RANK_ * 3 + 255) / 256, 256, 0, stream>>>(conv2_w, wqkv);
  gemm_mfma<1, 1><<<dim3(DIM_ / BN, SV_ / BM), 256, 0, stream>>>(
      gelup, nullptr, wqkv, nullptr, y2b, SV_, DIM_, RANK_ * 3, RANK_ * 3, RANK_ * 3, RANK_);

  // ---- fused QKV projection (bf16 out) ----
  wqkv_k<<<(3 * DIM_ * DIM_ + 255) / 256, 256, 0, stream>>>(to_q_w, to_k_w, to_v_w, wqkv);
  bqkv_k<<<(3 * DIM_ + 255) / 256, 256, 0, stream>>>(to_q_b, to_k_b, to_v_b, bqkv);
  const unsigned short* hid0 = hidpad + (size_t)256 * DIM_;
  gemm_mfma<2, 3><<<dim3(3 * DIM_ / BN, (S_ + BM - 1) / BM), 256, 0, stream>>>(
      encb, hid0, wqkv, bqkv, QKVbb, S_, 3 * DIM_, DIM_, DIM_, DIM_, 1);

  // ---- LN + RoPE (bf16 in place; Q scaled log2e/8) ----
  qknorm_rope<<<dim3((S_ * HEADS_ + 3) / 4, 2), 256, 0, stream>>>(
      Qbb, Kbb, nq_w, nq_b, nk_w, nk_b, cosT, sinT);

  // ---- MFMA flash attention (O bf16 over Qbb, conv-add fused) ----
  attn_mfma<<<dim3((S_ + 63) / 64, HEADS_), 256, 0, stream>>>(Qbb, Kbb, Vbb, y2b, Qbb);

  // ---- output projection -> d_out (fp32, tuple remap) ----
  cvt_w<<<(DIM_ * DIM_ + 255) / 256, 256, 0, stream>>>(to_out_w, wqkv, DIM_ * DIM_);
  gemm_mfma<0, 2><<<dim3(DIM_ / BN, (S_ + BM - 1) / BM), 256, 0, stream>>>(
      Qbb, nullptr, wqkv, to_out_b, out, S_, DIM_, DIM_, DIM_, DIM_, 1);
}

// Round 6
// 442.073 us; speedup vs baseline: 10.9870x; 1.0017x over previous
//
#include <hip/hip_runtime.h>
#include <hip/hip_bf16.h>
#include <math.h>

#define F_     8
#define DIM_   1920
#define HEADS_ 30
#define HD_    64
#define RANK_  128
#define T_     226
#define SV_    2048
#define S_     2274

#define BM 128
#define BN 128
#define BK 32

using short8 = __attribute__((ext_vector_type(8))) short;
using f32x4  = __attribute__((ext_vector_type(4))) float;
using i32x4v = __attribute__((ext_vector_type(4))) int;

__device__ __forceinline__ unsigned short f2b(float f) {
  unsigned int u = __float_as_uint(f);
  u = (u + 0x7FFFu + ((u >> 16) & 1u)) >> 16;
  return (unsigned short)u;
}
__device__ __forceinline__ float b2f(unsigned short s) {
  return __uint_as_float(((unsigned int)s) << 16);
}
__device__ __forceinline__ void gload_lds16(const void* g, void* l) {
  __builtin_amdgcn_global_load_lds(
      (const __attribute__((address_space(1))) unsigned int*)g,
      (__attribute__((address_space(3))) unsigned int*)l, 16, 0, 0);
}
// bijective XCD-aware swizzle (m204): consecutive remapped ids stay on one XCD
__device__ __forceinline__ void xcd_swz(int& bx, int& by) {
  const int nx = gridDim.x;
  const int nwg = nx * gridDim.y;
  const int lid = by * nx + bx;
  const int q = nwg >> 3, r = nwg & 7;
  const int xcd = lid & 7, pos = lid >> 3;
  const int wg = (xcd < r ? xcd * (q + 1) : r * (q + 1) + (xcd - r) * q) + pos;
  bx = wg % nx; by = wg / nx;
}

// ============================================================================
// MFMA bf16 GEMM:  C(MxN) = A(MxK) @ B(NxK)^T [+ bias]
// AMODE 0: A plain row-major, stride lda
// AMODE 1: conv shifts: col kk -> A[r + (kk/kinner)*256][kk%kinner]
// AMODE 2: concat rows: r<T_ -> A, else A2+(r-T_); lda=DIM_
// AMODE 3: conv1 split-K x12: z: A+=z*480 (1920=4*480), B row += (z>>2)*256,
//          B col += (z&3)*480, Cout partial z. Launch with K=480.
// OUTMODE 0: f32  1: bf16  2: f32 tuple-remap  3: bf16 QKV col-split
// ============================================================================
template<int AMODE, int OUTMODE>
__global__ __launch_bounds__(256) void gemm_mfma(
    const unsigned short* __restrict__ A,
    const unsigned short* __restrict__ A2,
    const unsigned short* __restrict__ B,
    const float* __restrict__ bias,
    void* __restrict__ Cout,
    int M, int N, int K, int lda, int ldb, int kinner)
{
  __shared__ __align__(16) unsigned short As[BM * BK];
  __shared__ __align__(16) unsigned short Bs[BN * BK];
  if constexpr (AMODE == 3) {
    const int z = blockIdx.z;
    A += (size_t)z * 480;
    B += (size_t)(z >> 2) * 256 * DIM_ + (z & 3) * 480;
    Cout = (void*)((float*)Cout + (size_t)z * M * N);
  }
  int bx = blockIdx.x, by = blockIdx.y;
  xcd_swz(bx, by);
  const int t   = threadIdx.x;
  const int w   = t >> 6, l = t & 63;
  const int wr  = w >> 1, wc = w & 1;
  const int row0 = by * BM, col0 = bx * BN;
  const int lr  = l & 15;
  const int lcg = l >> 4;
  const int sel = (lr >> 1) & 3;
  const int sr  = t >> 2;
  const int sc  = t & 3;

  f32x4 acc[4][4];
#pragma unroll
  for (int i = 0; i < 4; ++i)
#pragma unroll
    for (int j = 0; j < 4; ++j) acc[i][j] = (f32x4){0.f, 0.f, 0.f, 0.f};

  for (int k0 = 0; k0 < K; k0 += BK) {
    int kseg = 0, kcol = k0;
    if constexpr (AMODE == 1) { kseg = k0 / kinner; kcol = k0 - kseg * kinner; }
#pragma unroll
    for (int it = 0; it < 2; ++it) {
      const int r    = it * 64 + sr;
      const int csrc = sc ^ ((r >> 1) & 3);
      int ar = row0 + r; if (ar > M - 1) ar = M - 1;
      const unsigned short* asrc;
      if constexpr (AMODE == 1) {
        asrc = A + (size_t)(ar + kseg * 256) * kinner + kcol + csrc * 8;
      } else if constexpr (AMODE == 2) {
        asrc = (ar < T_) ? (A  + (size_t)ar        * DIM_ + k0 + csrc * 8)
                         : (A2 + (size_t)(ar - T_) * DIM_ + k0 + csrc * 8);
      } else {
        asrc = A + (size_t)ar * lda + k0 + csrc * 8;
      }
      gload_lds16(asrc, (char*)As + it * 4096 + t * 16);
      const unsigned short* bsrc = B + (size_t)(col0 + r) * ldb + k0 + csrc * 8;
      gload_lds16(bsrc, (char*)Bs + it * 4096 + t * 16);
    }
    __syncthreads();

    short8 af[4], bfv[4];
#pragma unroll
    for (int m = 0; m < 4; ++m) {
      int r = wr * 64 + m * 16 + lr;
      af[m] = *(const short8*)((const char*)As + r * 64 + ((lcg ^ sel) << 4));
    }
#pragma unroll
    for (int n = 0; n < 4; ++n) {
      int r = wc * 64 + n * 16 + lr;
      bfv[n] = *(const short8*)((const char*)Bs + r * 64 + ((lcg ^ sel) << 4));
    }
    __builtin_amdgcn_s_setprio(1);
#pragma unroll
    for (int m = 0; m < 4; ++m)
#pragma unroll
      for (int n = 0; n < 4; ++n)
        acc[m][n] = __builtin_amdgcn_mfma_f32_16x16x32_bf16(af[m], bfv[n], acc[m][n], 0, 0, 0);
    __builtin_amdgcn_s_setprio(0);
    __syncthreads();
  }

#pragma unroll
  for (int m = 0; m < 4; ++m) {
    const int rbase = row0 + wr * 64 + m * 16 + lcg * 4;
#pragma unroll
    for (int n = 0; n < 4; ++n) {
      const int c = col0 + wc * 64 + n * 16 + lr;
      const float bi = bias ? bias[c] : 0.f;
#pragma unroll
      for (int reg = 0; reg < 4; ++reg) {
        const int r = rbase + reg;
        if (r >= M) continue;
        const float v = acc[m][n][reg] + bi;
        if constexpr (OUTMODE == 0) {
          ((float*)Cout)[(size_t)r * N + c] = v;
        } else if constexpr (OUTMODE == 1) {
          ((unsigned short*)Cout)[(size_t)r * N + c] = f2b(v);
        } else if constexpr (OUTMODE == 2) {
          const size_t orow = (r >= T_) ? (size_t)(r - T_) : (size_t)(SV_ + r);
          ((float*)Cout)[orow * N + c] = v;
        } else {
          const int buf = c / DIM_, cc = c - buf * DIM_;
          ((unsigned short*)Cout)[(size_t)buf * S_ * DIM_ + (size_t)r * DIM_ + cc] = f2b(v);
        }
      }
    }
  }
}

// ============================================================================
// MFMA flash attention, swapped QK^T + in-register softmax/P (exp2 domain).
// Double-buffered async staging: K via global_load_lds, V via reg-stage
// (issue-early / ds_write-late, T14). One barrier per KV tile.
// Conv-branch add fused into the epilogue (rows >= T_).
// ============================================================================
__global__ __launch_bounds__(256) void attn_mfma(
    const unsigned short* __restrict__ Qbb,
    const unsigned short* __restrict__ Kbb,
    const unsigned short* __restrict__ Vbb,
    const unsigned short* __restrict__ y2b,
    unsigned short* __restrict__ O)
{
  __shared__ __align__(16) unsigned short Kl[2][64 * 64];   // [key][d], swz 16B
  __shared__ __align__(16) unsigned short Vt[2][64 * 64];   // [d][key], swz 8-elt

  int bx = blockIdx.x, by = blockIdx.y;
  xcd_swz(bx, by);                       // groups same-head q-blocks per XCD
  const int qb = bx, h = by;
  const int t = threadIdx.x, w = t >> 6, l = t & 63;
  const int lr = l & 15, lg = l >> 4;
  const int q0 = qb * 64;

  short8 qa[2];
  {
    int qrow = q0 + w * 16 + lr; if (qrow >= S_) qrow = S_ - 1;
    const unsigned short* qp = Qbb + (size_t)qrow * DIM_ + h * 64 + lg * 8;
    qa[0] = *(const short8*)qp;
    qa[1] = *(const short8*)(qp + 32);
  }

  // staging address pieces (constant per thread)
  const int krow0 = t >> 3;              // K-stage row, it=0 (+32 for it=1)
  const int kc0 = ((((t & 7) * 16) ^ ((krow0        & 7) << 4)) >> 1);
  const int kc1 = ((((t & 7) * 16) ^ (((krow0 + 32) & 7) << 4)) >> 1);

  f32x4 oacc[4];
#pragma unroll
  for (int n = 0; n < 4; ++n) oacc[n] = (f32x4){0.f, 0.f, 0.f, 0.f};
  float m_run = -1e30f, l_run = 0.f;

  const int addrA = (lr + ((lg & 1) << 5)) << 2;   // bpermute src lane*4
  const bool hi_m = (lg & 2) != 0;                 // selects c[2ks+1]

  const int NT = (S_ + 63) / 64;

  // ---- prologue: stage tile 0 ----
  {
    int k0 = 0 + krow0;      if (k0 >= S_) k0 = S_ - 1;
    int k1 = 0 + krow0 + 32; if (k1 >= S_) k1 = S_ - 1;
    gload_lds16(Kbb + (size_t)k0 * DIM_ + h * 64 + kc0, (char*)Kl[0] + t * 16);
    gload_lds16(Kbb + (size_t)k1 * DIM_ + h * 64 + kc1, (char*)Kl[0] + 4096 + t * 16);
    int key = l; if (key >= S_) key = S_ - 1;
    const unsigned short* vp = Vbb + (size_t)key * DIM_ + h * 64 + w * 16;
    short8 v0 = *(const short8*)vp;
    short8 v1 = *(const short8*)(vp + 8);
#pragma unroll
    for (int i = 0; i < 8; ++i)
      Vt[0][(w * 16 + i) * 64 + (l ^ ((i & 7) << 3))] = (unsigned short)v0[i];
#pragma unroll
    for (int i = 8; i < 16; ++i)
      Vt[0][(w * 16 + i) * 64 + (l ^ ((i & 7) << 3))] = (unsigned short)v1[i - 8];
  }
  __syncthreads();

  for (int jt = 0; jt < NT; ++jt) {
    const int j0 = jt * 64;
    const int cur = jt & 1;

    // ---- issue prefetch for tile jt+1 (clamped re-read on last iter) ----
    const int jn0 = (jt + 1 < NT) ? (jt + 1) * 64 : jt * 64;
    {
      int k0 = jn0 + krow0;      if (k0 >= S_) k0 = S_ - 1;
      int k1 = jn0 + krow0 + 32; if (k1 >= S_) k1 = S_ - 1;
      gload_lds16(Kbb + (size_t)k0 * DIM_ + h * 64 + kc0,
                  (char*)Kl[cur ^ 1] + t * 16);
      gload_lds16(Kbb + (size_t)k1 * DIM_ + h * 64 + kc1,
                  (char*)Kl[cur ^ 1] + 4096 + t * 16);
    }
    short8 nv0, nv1;
    {
      int key = jn0 + l; if (key >= S_) key = S_ - 1;
      const unsigned short* vp = Vbb + (size_t)key * DIM_ + h * 64 + w * 16;
      nv0 = *(const short8*)vp;
      nv1 = *(const short8*)(vp + 8);
    }

    // ---- S^T = K @ Q^T : lane holds S[key = m*16+lg*4+r][q = lr] ----
    f32x4 sacc[4];
#pragma unroll
    for (int m = 0; m < 4; ++m) sacc[m] = (f32x4){0.f, 0.f, 0.f, 0.f};
    __builtin_amdgcn_s_setprio(1);
#pragma unroll
    for (int m = 0; m < 4; ++m) {
#pragma unroll
      for (int ks = 0; ks < 2; ++ks) {
        const short8 kb = *(const short8*)((const char*)Kl[cur] + (m * 16 + lr) * 128 +
                              ((ks * 64 + lg * 16) ^ ((lr & 7) << 4)));
        sacc[m] = __builtin_amdgcn_mfma_f32_16x16x32_bf16(kb, qa[ks], sacc[m], 0, 0, 0);
      }
    }
    __builtin_amdgcn_s_setprio(0);
    if (j0 + 64 > S_) {
#pragma unroll
      for (int m = 0; m < 4; ++m)
#pragma unroll
        for (int r = 0; r < 4; ++r)
          if (j0 + m * 16 + lg * 4 + r >= S_) sacc[m][r] = -1e30f;
    }

    // ---- row max: 15 in-lane + 2 shuffles ----
    float mx = sacc[0][0];
#pragma unroll
    for (int m = 0; m < 4; ++m)
#pragma unroll
      for (int r = 0; r < 4; ++r) mx = fmaxf(mx, sacc[m][r]);
    mx = fmaxf(mx, __shfl_xor(mx, 16));
    mx = fmaxf(mx, __shfl_xor(mx, 32));

    // ---- defer-max rescale (exp2 domain, THR=8) ----
    if (!__all(mx <= m_run + 8.0f)) {
      const float mnew = fmaxf(m_run, mx);
      const float sc = exp2f(m_run - mnew);
      l_run *= sc;
      float scr[4];
#pragma unroll
      for (int r = 0; r < 4; ++r) scr[r] = __shfl(sc, (l & 48) | (lg * 4 + r));
#pragma unroll
      for (int n = 0; n < 4; ++n)
#pragma unroll
        for (int r = 0; r < 4; ++r) oacc[n][r] *= scr[r];
      m_run = mnew;
    }

    // ---- P = exp2(S - m), packed to bf16 pairs in-register ----
    float rs = 0.f;
    int c[4][2];
#pragma unroll
    for (int m = 0; m < 4; ++m) {
      const float p0 = exp2f(sacc[m][0] - m_run);
      const float p1 = exp2f(sacc[m][1] - m_run);
      const float p2 = exp2f(sacc[m][2] - m_run);
      const float p3 = exp2f(sacc[m][3] - m_run);
      rs += (p0 + p1) + (p2 + p3);
      asm("v_cvt_pk_bf16_f32 %0, %1, %2" : "=v"(c[m][0]) : "v"(p0), "v"(p1));
      asm("v_cvt_pk_bf16_f32 %0, %1, %2" : "=v"(c[m][1]) : "v"(p2), "v"(p3));
    }
    rs += __shfl_xor(rs, 16);
    rs += __shfl_xor(rs, 32);
    l_run += rs;

    // ---- build P A-frags via bpermute exchange, then O += P @ V ----
    __builtin_amdgcn_s_setprio(1);
#pragma unroll
    for (int ks = 0; ks < 2; ++ks) {
      const int a0 = __builtin_amdgcn_ds_bpermute(addrA,      c[2 * ks][0]);
      const int b0 = __builtin_amdgcn_ds_bpermute(addrA,      c[2 * ks + 1][0]);
      const int a1 = __builtin_amdgcn_ds_bpermute(addrA,      c[2 * ks][1]);
      const int b1 = __builtin_amdgcn_ds_bpermute(addrA,      c[2 * ks + 1][1]);
      const int a2 = __builtin_amdgcn_ds_bpermute(addrA + 64, c[2 * ks][0]);
      const int b2 = __builtin_amdgcn_ds_bpermute(addrA + 64, c[2 * ks + 1][0]);
      const int a3 = __builtin_amdgcn_ds_bpermute(addrA + 64, c[2 * ks][1]);
      const int b3 = __builtin_amdgcn_ds_bpermute(addrA + 64, c[2 * ks + 1][1]);
      i32x4v pw;
      pw[0] = hi_m ? b0 : a0;
      pw[1] = hi_m ? b1 : a1;
      pw[2] = hi_m ? b2 : a2;
      pw[3] = hi_m ? b3 : a3;
      const short8 pa = __builtin_bit_cast(short8, pw);
#pragma unroll
      for (int n = 0; n < 4; ++n) {
        const short8 vb = *(const short8*)((const char*)Vt[cur] + (n * 16 + lr) * 128 +
                              ((ks * 64 + lg * 16) ^ ((lr & 7) << 4)));
        oacc[n] = __builtin_amdgcn_mfma_f32_16x16x32_bf16(pa, vb, oacc[n], 0, 0, 0);
      }
    }
    __builtin_amdgcn_s_setprio(0);

    // ---- late V write into the other buffer (waits its global loads) ----
#pragma unroll
    for (int i = 0; i < 8; ++i)
      Vt[cur ^ 1][(w * 16 + i) * 64 + (l ^ ((i & 7) << 3))] = (unsigned short)nv0[i];
#pragma unroll
    for (int i = 8; i < 16; ++i)
      Vt[cur ^ 1][(w * 16 + i) * 64 + (l ^ ((i & 7) << 3))] = (unsigned short)nv1[i - 8];
    __syncthreads();     // drains K-DMA (vmcnt) + Vt writes for next iter
  }

  // ---- epilogue: divide by l, add conv branch (rows >= T_), store bf16 ----
  const float invl = 1.f / l_run;
  float ir[4];
#pragma unroll
  for (int r = 0; r < 4; ++r) ir[r] = __shfl(invl, (l & 48) | (lg * 4 + r));
#pragma unroll
  for (int r = 0; r < 4; ++r) {
    const int row = q0 + w * 16 + lg * 4 + r;
    if (row >= S_) continue;
#pragma unroll
    for (int n = 0; n < 4; ++n) {
      const int col = h * 64 + n * 16 + lr;
      float v = oacc[n][r] * ir[r];
      if (row >= T_) v += b2f(y2b[(size_t)(row - T_) * DIM_ + col]);
      O[(size_t)row * DIM_ + col] = f2b(v);
    }
  }
}

// ============================================================================
// small kernels
// ============================================================================
__global__ void cvt_w(const float* __restrict__ src, unsigned short* __restrict__ dst, int n)
{
  int i = blockIdx.x * 256 + threadIdx.x;
  if (i < n) dst[i] = f2b(src[i]);
}

__global__ void hidpad_k(const float* __restrict__ hid, unsigned short* __restrict__ dst)
{
  int i = blockIdx.x * 256 + threadIdx.x;
  if (i >= 2560 * DIM_) return;
  int r = i / DIM_;
  dst[i] = (r >= 256 && r < 256 + SV_) ? f2b(hid[i - 256 * DIM_]) : 0;
}

__global__ void encb_k(const float* __restrict__ enc, unsigned short* __restrict__ dst)
{
  int i = blockIdx.x * 256 + threadIdx.x;
  if (i < T_ * DIM_) dst[i] = f2b(enc[i]);
}

__global__ void w1p_k(const float* __restrict__ src, unsigned short* __restrict__ dst)
{
  int i = blockIdx.x * 256 + threadIdx.x;           // over 128*5760
  if (i >= RANK_ * DIM_ * 3) return;
  int oc = i / (DIM_ * 3), rem = i % (DIM_ * 3);
  int ks = rem / DIM_, ic = rem % DIM_;
  dst[i] = f2b(src[(size_t)oc * DIM_ * 3 + ic * 3 + ks]);
}

__global__ void w2p_k(const float* __restrict__ src, unsigned short* __restrict__ dst)
{
  int i = blockIdx.x * 256 + threadIdx.x;           // over 1920*384
  if (i >= DIM_ * RANK_ * 3) return;
  int oc = i / (RANK_ * 3), rem = i % (RANK_ * 3);
  int ks = rem / RANK_, rc = rem % RANK_;
  dst[i] = f2b(src[(size_t)oc * RANK_ * 3 + rc * 3 + ks]);
}

__global__ void wqkv_k(const float* __restrict__ q, const float* __restrict__ k,
                       const float* __restrict__ v, unsigned short* __restrict__ dst)
{
  int i = blockIdx.x * 256 + threadIdx.x;           // over 3*DIM*DIM
  if (i >= 3 * DIM_ * DIM_) return;
  int which = i / (DIM_ * DIM_), j = i % (DIM_ * DIM_);
  const float* s = which == 0 ? q : which == 1 ? k : v;
  dst[i] = f2b(s[j]);
}

__global__ void bqkv_k(const float* __restrict__ q, const float* __restrict__ k,
                       const float* __restrict__ v, float* __restrict__ dst)
{
  int i = blockIdx.x * 256 + threadIdx.x;           // over 3*DIM
  if (i >= 3 * DIM_) return;
  int which = i / DIM_, j = i % DIM_;
  dst[i] = which == 0 ? q[j] : which == 1 ? k[j] : v[j];
}

// sum 12 split-K partials of y1^T [128][2048], GELU, write padded [2560][128]
__global__ void gelupad_k(const float* __restrict__ y1T, unsigned short* __restrict__ dst)
{
  int i = blockIdx.x * 256 + threadIdx.x;           // over 2560*128
  if (i >= 2560 * RANK_) return;
  int r = i / RANK_, rc = i % RANK_;
  unsigned short o = 0;
  if (r >= 256 && r < 256 + SV_) {
    int s = r - 256;
    float x = 0.f;
#pragma unroll
    for (int z = 0; z < 12; ++z)
      x += y1T[(size_t)z * RANK_ * SV_ + (size_t)rc * SV_ + s];
    o = f2b(0.5f * x * (1.f + erff(x * 0.70710678118654752f)));
  }
  dst[i] = o;
}

// LN over HD=64 + RoPE, bf16 in place; Q branch scaled by log2(e)/8
__global__ __launch_bounds__(256) void qknorm_rope(
    unsigned short* __restrict__ Qbb, unsigned short* __restrict__ Kbb,
    const float* __restrict__ nq_w, const float* __restrict__ nq_b,
    const float* __restrict__ nk_w, const float* __restrict__ nk_b,
    const float* __restrict__ cosT, const float* __restrict__ sinT)
{
  const int w = threadIdx.x >> 6, lane = threadIdx.x & 63;
  const int idx = blockIdx.x * 4 + w;
  if (idx >= S_ * HEADS_) return;
  const int s = idx / HEADS_, h = idx % HEADS_;
  unsigned short* X = blockIdx.y ? Kbb : Qbb;
  const float* wt = blockIdx.y ? nk_w : nq_w;
  const float* bt = blockIdx.y ? nk_b : nq_b;
  const size_t off = (size_t)s * DIM_ + h * HD_ + lane;
  float x = b2f(X[off]);
  float m = x;
#pragma unroll
  for (int o = 32; o; o >>= 1) m += __shfl_xor(m, o);
  m *= (1.f / 64.f);
  float d = x - m;
  float v = d * d;
#pragma unroll
  for (int o = 32; o; o >>= 1) v += __shfl_xor(v, o);
  v *= (1.f / 64.f);
  float y = d * rsqrtf(v + 1e-6f) * wt[lane] + bt[lane];
  if (s >= T_) {
    float p = __shfl_xor(y, 1);
    float rot = (lane & 1) ? p : -p;
    int sv = s - T_;
    y = y * cosT[(size_t)sv * HD_ + lane] + rot * sinT[(size_t)sv * HD_ + lane];
  }
  if (!blockIdx.y) y *= 0.18033688011112042f;   // (1/8) * log2(e)
  X[off] = f2b(y);
}

// ============================================================================
extern "C" void kernel_launch(void* const* d_in, const int* in_sizes, int n_in,
                              void* d_out, int out_size, void* d_ws, size_t ws_size,
                              hipStream_t stream)
{
  const float* hidden  = (const float*)d_in[0];
  const float* encoder = (const float*)d_in[1];
  const float* cosT    = (const float*)d_in[2];
  const float* sinT    = (const float*)d_in[3];
  const float* to_q_w  = (const float*)d_in[4];
  const float* to_q_b  = (const float*)d_in[5];
  const float* to_k_w  = (const float*)d_in[6];
  const float* to_k_b  = (const float*)d_in[7];
  const float* to_v_w  = (const float*)d_in[8];
  const float* to_v_b  = (const float*)d_in[9];
  const float* nq_w    = (const float*)d_in[10];
  const float* nq_b    = (const float*)d_in[11];
  const float* nk_w    = (const float*)d_in[12];
  const float* nk_b    = (const float*)d_in[13];
  const float* conv1_w = (const float*)d_in[14];
  const float* conv2_w = (const float*)d_in[15];
  const float* to_out_w = (const float*)d_in[16];
  const float* to_out_b = (const float*)d_in[17];
  float* out = (float*)d_out;

  // ---- workspace layout (~80.1 MB; >=85.59 MB proven available) ----
  char* p = (char*)d_ws;
  unsigned short* hidpad = (unsigned short*)p;  p += (size_t)2560 * DIM_ * 2;        // 9.83 MB
  unsigned short* y2b    = (unsigned short*)p;  p += (size_t)SV_ * DIM_ * 2;         // 7.86 MB
  unsigned short* wqkv   = (unsigned short*)p;  p += (size_t)3 * DIM_ * DIM_ * 2;    // 22.1 MB
  unsigned short* QKVbb  = (unsigned short*)p;  p += (size_t)3 * S_ * DIM_ * 2;      // 26.2 MB
  unsigned short* encb   = (unsigned short*)p;  p += (size_t)T_ * DIM_ * 2;          // 0.87 MB
  float*          y1T    = (float*)p;           p += (size_t)12 * RANK_ * SV_ * 4;   // 12.6 MB
  unsigned short* gelup  = (unsigned short*)p;  p += (size_t)2560 * RANK_ * 2;       // 0.66 MB
  float*          bqkv   = (float*)p;           p += (size_t)3 * DIM_ * 4;           // 23 KB
  unsigned short* Qbb = QKVbb;
  unsigned short* Kbb = QKVbb + (size_t)S_ * DIM_;
  unsigned short* Vbb = QKVbb + (size_t)2 * S_ * DIM_;

  // ---- input conversions ----
  hidpad_k<<<(2560 * DIM_ + 255) / 256, 256, 0, stream>>>(hidden, hidpad);
  encb_k<<<(T_ * DIM_ + 255) / 256, 256, 0, stream>>>(encoder, encb);

  // ---- conv branch ----
  w1p_k<<<(RANK_ * DIM_ * 3 + 255) / 256, 256, 0, stream>>>(conv1_w, wqkv);
  gemm_mfma<3, 0><<<dim3(SV_ / BN, 1, 12), 256, 0, stream>>>(
      wqkv, nullptr, hidpad, nullptr, y1T, RANK_, SV_, 480, DIM_ * 3, DIM_, 1);
  gelupad_k<<<(2560 * RANK_ + 255) / 256, 256, 0, stream>>>(y1T, gelup);
  w2p_k<<<(DIM_ * RANK_ * 3 + 255) / 256, 256, 0, stream>>>(conv2_w, wqkv);
  gemm_mfma<1, 1><<<dim3(DIM_ / BN, SV_ / BM), 256, 0, stream>>>(
      gelup, nullptr, wqkv, nullptr, y2b, SV_, DIM_, RANK_ * 3, RANK_ * 3, RANK_ * 3, RANK_);

  // ---- fused QKV projection (bf16 out) ----
  wqkv_k<<<(3 * DIM_ * DIM_ + 255) / 256, 256, 0, stream>>>(to_q_w, to_k_w, to_v_w, wqkv);
  bqkv_k<<<(3 * DIM_ + 255) / 256, 256, 0, stream>>>(to_q_b, to_k_b, to_v_b, bqkv);
  const unsigned short* hid0 = hidpad + (size_t)256 * DIM_;
  gemm_mfma<2, 3><<<dim3(3 * DIM_ / BN, (S_ + BM - 1) / BM), 256, 0, stream>>>(
      encb, hid0, wqkv, bqkv, QKVbb, S_, 3 * DIM_, DIM_, DIM_, DIM_, 1);

  // ---- LN + RoPE (bf16 in place; Q scaled log2e/8) ----
  qknorm_rope<<<dim3((S_ * HEADS_ + 3) / 4, 2), 256, 0, stream>>>(
      Qbb, Kbb, nq_w, nq_b, nk_w, nk_b, cosT, sinT);

  // ---- MFMA flash attention (O bf16 over Qbb, conv-add fused) ----
  attn_mfma<<<dim3((S_ + 63) / 64, HEADS_), 256, 0, stream>>>(Qbb, Kbb, Vbb, y2b, Qbb);

  // ---- output projection -> d_out (fp32, tuple remap) ----
  cvt_w<<<(DIM_ * DIM_ + 255) / 256, 256, 0, stream>>>(to_out_w, wqkv, DIM_ * DIM_);
  gemm_mfma<0, 2><<<dim3(DIM_ / BN, (S_ + BM - 1) / BM), 256, 0, stream>>>(
      Qbb, nullptr, wqkv, to_out_b, out, S_, DIM_, DIM_, DIM_, DIM_, 1);
}

// Round 7
// 406.239 us; speedup vs baseline: 11.9562x; 1.0882x over previous
//
#include <hip/hip_runtime.h>
#include <hip/hip_bf16.h>
#include <math.h>

#define F_     8
#define DIM_   1920
#define HEADS_ 30
#define HD_    64
#define RANK_  128
#define T_     226
#define SV_    2048
#define S_     2274

#define BM 128
#define BN 128
#define BK 32

using short8  = __attribute__((ext_vector_type(8))) short;
using f32x4   = __attribute__((ext_vector_type(4))) float;
using i32x4v  = __attribute__((ext_vector_type(4))) int;
using ushort4v= __attribute__((ext_vector_type(4))) unsigned short;

__device__ __forceinline__ unsigned short f2b(float f) {
  unsigned int u = __float_as_uint(f);
  u = (u + 0x7FFFu + ((u >> 16) & 1u)) >> 16;
  return (unsigned short)u;
}
__device__ __forceinline__ float b2f(unsigned short s) {
  return __uint_as_float(((unsigned int)s) << 16);
}
__device__ __forceinline__ void gload_lds16(const void* g, void* l) {
  __builtin_amdgcn_global_load_lds(
      (const __attribute__((address_space(1))) unsigned int*)g,
      (__attribute__((address_space(3))) unsigned int*)l, 16, 0, 0);
}
// bijective XCD-aware swizzle (m204)
__device__ __forceinline__ void xcd_swz(int& bx, int& by) {
  const int nx = gridDim.x;
  const int nwg = nx * gridDim.y;
  const int lid = by * nx + bx;
  const int q = nwg >> 3, r = nwg & 7;
  const int xcd = lid & 7, pos = lid >> 3;
  const int wg = (xcd < r ? xcd * (q + 1) : r * (q + 1) + (xcd - r) * q) + pos;
  bx = wg % nx; by = wg / nx;
}

// ============================================================================
// MFMA bf16 GEMM:  C(MxN) = A(MxK) @ B(NxK)^T [+ bias]
// AMODE 0: plain A; 1: conv shifts; 2: concat rows; 3: conv1 split-K x12
// OUTMODE 0: f32  1: bf16  2: f32 tuple-remap  3: bf16 QKV col-split
// ============================================================================
template<int AMODE, int OUTMODE>
__global__ __launch_bounds__(256) void gemm_mfma(
    const unsigned short* __restrict__ A,
    const unsigned short* __restrict__ A2,
    const unsigned short* __restrict__ B,
    const float* __restrict__ bias,
    void* __restrict__ Cout,
    int M, int N, int K, int lda, int ldb, int kinner)
{
  __shared__ __align__(16) unsigned short As[BM * BK];
  __shared__ __align__(16) unsigned short Bs[BN * BK];
  if constexpr (AMODE == 3) {
    const int z = blockIdx.z;
    A += (size_t)z * 480;
    B += (size_t)(z >> 2) * 256 * DIM_ + (z & 3) * 480;
    Cout = (void*)((float*)Cout + (size_t)z * M * N);
  }
  int bx = blockIdx.x, by = blockIdx.y;
  xcd_swz(bx, by);
  const int t   = threadIdx.x;
  const int w   = t >> 6, l = t & 63;
  const int wr  = w >> 1, wc = w & 1;
  const int row0 = by * BM, col0 = bx * BN;
  const int lr  = l & 15;
  const int lcg = l >> 4;
  const int sel = (lr >> 1) & 3;
  const int sr  = t >> 2;
  const int sc  = t & 3;

  f32x4 acc[4][4];
#pragma unroll
  for (int i = 0; i < 4; ++i)
#pragma unroll
    for (int j = 0; j < 4; ++j) acc[i][j] = (f32x4){0.f, 0.f, 0.f, 0.f};

  for (int k0 = 0; k0 < K; k0 += BK) {
    int kseg = 0, kcol = k0;
    if constexpr (AMODE == 1) { kseg = k0 / kinner; kcol = k0 - kseg * kinner; }
#pragma unroll
    for (int it = 0; it < 2; ++it) {
      const int r    = it * 64 + sr;
      const int csrc = sc ^ ((r >> 1) & 3);
      int ar = row0 + r; if (ar > M - 1) ar = M - 1;
      const unsigned short* asrc;
      if constexpr (AMODE == 1) {
        asrc = A + (size_t)(ar + kseg * 256) * kinner + kcol + csrc * 8;
      } else if constexpr (AMODE == 2) {
        asrc = (ar < T_) ? (A  + (size_t)ar        * DIM_ + k0 + csrc * 8)
                         : (A2 + (size_t)(ar - T_) * DIM_ + k0 + csrc * 8);
      } else {
        asrc = A + (size_t)ar * lda + k0 + csrc * 8;
      }
      gload_lds16(asrc, (char*)As + it * 4096 + t * 16);
      const unsigned short* bsrc = B + (size_t)(col0 + r) * ldb + k0 + csrc * 8;
      gload_lds16(bsrc, (char*)Bs + it * 4096 + t * 16);
    }
    __syncthreads();

    short8 af[4], bfv[4];
#pragma unroll
    for (int m = 0; m < 4; ++m) {
      int r = wr * 64 + m * 16 + lr;
      af[m] = *(const short8*)((const char*)As + r * 64 + ((lcg ^ sel) << 4));
    }
#pragma unroll
    for (int n = 0; n < 4; ++n) {
      int r = wc * 64 + n * 16 + lr;
      bfv[n] = *(const short8*)((const char*)Bs + r * 64 + ((lcg ^ sel) << 4));
    }
    __builtin_amdgcn_s_setprio(1);
#pragma unroll
    for (int m = 0; m < 4; ++m)
#pragma unroll
      for (int n = 0; n < 4; ++n)
        acc[m][n] = __builtin_amdgcn_mfma_f32_16x16x32_bf16(af[m], bfv[n], acc[m][n], 0, 0, 0);
    __builtin_amdgcn_s_setprio(0);
    __syncthreads();
  }

#pragma unroll
  for (int m = 0; m < 4; ++m) {
    const int rbase = row0 + wr * 64 + m * 16 + lcg * 4;
#pragma unroll
    for (int n = 0; n < 4; ++n) {
      const int c = col0 + wc * 64 + n * 16 + lr;
      const float bi = bias ? bias[c] : 0.f;
#pragma unroll
      for (int reg = 0; reg < 4; ++reg) {
        const int r = rbase + reg;
        if (r >= M) continue;
        const float v = acc[m][n][reg] + bi;
        if constexpr (OUTMODE == 0) {
          ((float*)Cout)[(size_t)r * N + c] = v;
        } else if constexpr (OUTMODE == 1) {
          ((unsigned short*)Cout)[(size_t)r * N + c] = f2b(v);
        } else if constexpr (OUTMODE == 2) {
          const size_t orow = (r >= T_) ? (size_t)(r - T_) : (size_t)(SV_ + r);
          ((float*)Cout)[orow * N + c] = v;
        } else {
          const int buf = c / DIM_, cc = c - buf * DIM_;
          ((unsigned short*)Cout)[(size_t)buf * S_ * DIM_ + (size_t)r * DIM_ + cc] = f2b(v);
        }
      }
    }
  }
}

// ============================================================================
// MFMA flash attention, split-S x2. Block = (q-tile, head, sv half).
// Swapped QK^T, in-register softmax (exp2 domain), defer-max, dbuf staging.
// Writes UNNORMALIZED O-partial (bf16) + per-(q,h) {m,l} (f32) for LSE merge.
// ============================================================================
__global__ __launch_bounds__(256) void attn_mfma(
    const unsigned short* __restrict__ Qbb,
    const unsigned short* __restrict__ Kbb,
    const unsigned short* __restrict__ Vbb,
    unsigned short* __restrict__ Op0,
    unsigned short* __restrict__ Op1,
    float* __restrict__ ml)
{
  __shared__ __align__(16) unsigned short Kl[2][64 * 64];   // [key][d], swz 16B
  __shared__ __align__(16) unsigned short Vt[2][64 * 64];   // [d][key], swz 8-elt

  const int sv = blockIdx.z;
  int bx = blockIdx.x, by = blockIdx.y;
  xcd_swz(bx, by);
  const int qb = bx, h = by;
  const int t = threadIdx.x, w = t >> 6, l = t & 63;
  const int lr = l & 15, lg = l >> 4;
  const int q0 = qb * 64;
  const int j0base = sv * 1152;
  const int NT = 18;
  unsigned short* Opart = sv ? Op1 : Op0;

  short8 qa[2];
  {
    int qrow = q0 + w * 16 + lr; if (qrow >= S_) qrow = S_ - 1;
    const unsigned short* qp = Qbb + (size_t)qrow * DIM_ + h * 64 + lg * 8;
    qa[0] = *(const short8*)qp;
    qa[1] = *(const short8*)(qp + 32);
  }

  const int krow0 = t >> 3;
  const int kc0 = ((((t & 7) * 16) ^ ((krow0        & 7) << 4)) >> 1);
  const int kc1 = ((((t & 7) * 16) ^ (((krow0 + 32) & 7) << 4)) >> 1);

  f32x4 oacc[4];
#pragma unroll
  for (int n = 0; n < 4; ++n) oacc[n] = (f32x4){0.f, 0.f, 0.f, 0.f};
  float m_run = -1e30f, l_run = 0.f;

  const int addrA = (lr + ((lg & 1) << 5)) << 2;
  const bool hi_m = (lg & 2) != 0;

  // ---- prologue: stage tile 0 of this half ----
  {
    int k0 = j0base + krow0;      if (k0 >= S_) k0 = S_ - 1;
    int k1 = j0base + krow0 + 32; if (k1 >= S_) k1 = S_ - 1;
    gload_lds16(Kbb + (size_t)k0 * DIM_ + h * 64 + kc0, (char*)Kl[0] + t * 16);
    gload_lds16(Kbb + (size_t)k1 * DIM_ + h * 64 + kc1, (char*)Kl[0] + 4096 + t * 16);
    int key = j0base + l; if (key >= S_) key = S_ - 1;
    const unsigned short* vp = Vbb + (size_t)key * DIM_ + h * 64 + w * 16;
    short8 v0 = *(const short8*)vp;
    short8 v1 = *(const short8*)(vp + 8);
#pragma unroll
    for (int i = 0; i < 8; ++i)
      Vt[0][(w * 16 + i) * 64 + (l ^ ((i & 7) << 3))] = (unsigned short)v0[i];
#pragma unroll
    for (int i = 8; i < 16; ++i)
      Vt[0][(w * 16 + i) * 64 + (l ^ ((i & 7) << 3))] = (unsigned short)v1[i - 8];
  }
  __syncthreads();

  for (int jt = 0; jt < NT; ++jt) {
    const int j0 = j0base + jt * 64;
    const int cur = jt & 1;

    // ---- issue prefetch for next tile (clamped re-read on last iter) ----
    const int jn0 = (jt + 1 < NT) ? j0 + 64 : j0;
    {
      int k0 = jn0 + krow0;      if (k0 >= S_) k0 = S_ - 1;
      int k1 = jn0 + krow0 + 32; if (k1 >= S_) k1 = S_ - 1;
      gload_lds16(Kbb + (size_t)k0 * DIM_ + h * 64 + kc0,
                  (char*)Kl[cur ^ 1] + t * 16);
      gload_lds16(Kbb + (size_t)k1 * DIM_ + h * 64 + kc1,
                  (char*)Kl[cur ^ 1] + 4096 + t * 16);
    }
    short8 nv0, nv1;
    {
      int key = jn0 + l; if (key >= S_) key = S_ - 1;
      const unsigned short* vp = Vbb + (size_t)key * DIM_ + h * 64 + w * 16;
      nv0 = *(const short8*)vp;
      nv1 = *(const short8*)(vp + 8);
    }

    // ---- S^T = K @ Q^T : lane holds S[key = m*16+lg*4+r][q = lr] ----
    f32x4 sacc[4];
#pragma unroll
    for (int m = 0; m < 4; ++m) sacc[m] = (f32x4){0.f, 0.f, 0.f, 0.f};
    __builtin_amdgcn_s_setprio(1);
#pragma unroll
    for (int m = 0; m < 4; ++m) {
#pragma unroll
      for (int ks = 0; ks < 2; ++ks) {
        const short8 kb = *(const short8*)((const char*)Kl[cur] + (m * 16 + lr) * 128 +
                              ((ks * 64 + lg * 16) ^ ((lr & 7) << 4)));
        sacc[m] = __builtin_amdgcn_mfma_f32_16x16x32_bf16(kb, qa[ks], sacc[m], 0, 0, 0);
      }
    }
    __builtin_amdgcn_s_setprio(0);
    if (j0 + 64 > S_) {
#pragma unroll
      for (int m = 0; m < 4; ++m)
#pragma unroll
        for (int r = 0; r < 4; ++r)
          if (j0 + m * 16 + lg * 4 + r >= S_) sacc[m][r] = -1e30f;
    }

    // ---- row max ----
    float mx = sacc[0][0];
#pragma unroll
    for (int m = 0; m < 4; ++m)
#pragma unroll
      for (int r = 0; r < 4; ++r) mx = fmaxf(mx, sacc[m][r]);
    mx = fmaxf(mx, __shfl_xor(mx, 16));
    mx = fmaxf(mx, __shfl_xor(mx, 32));

    // ---- defer-max rescale (exp2 domain, THR=8) ----
    if (!__all(mx <= m_run + 8.0f)) {
      const float mnew = fmaxf(m_run, mx);
      const float sc = exp2f(m_run - mnew);
      l_run *= sc;
      float scr[4];
#pragma unroll
      for (int r = 0; r < 4; ++r) scr[r] = __shfl(sc, (l & 48) | (lg * 4 + r));
#pragma unroll
      for (int n = 0; n < 4; ++n)
#pragma unroll
        for (int r = 0; r < 4; ++r) oacc[n][r] *= scr[r];
      m_run = mnew;
    }

    // ---- P = exp2(S - m), packed to bf16 pairs in-register ----
    float rs = 0.f;
    int c[4][2];
#pragma unroll
    for (int m = 0; m < 4; ++m) {
      const float p0 = exp2f(sacc[m][0] - m_run);
      const float p1 = exp2f(sacc[m][1] - m_run);
      const float p2 = exp2f(sacc[m][2] - m_run);
      const float p3 = exp2f(sacc[m][3] - m_run);
      rs += (p0 + p1) + (p2 + p3);
      asm("v_cvt_pk_bf16_f32 %0, %1, %2" : "=v"(c[m][0]) : "v"(p0), "v"(p1));
      asm("v_cvt_pk_bf16_f32 %0, %1, %2" : "=v"(c[m][1]) : "v"(p2), "v"(p3));
    }
    rs += __shfl_xor(rs, 16);
    rs += __shfl_xor(rs, 32);
    l_run += rs;

    // ---- P A-frags via bpermute exchange, then O += P @ V ----
    __builtin_amdgcn_s_setprio(1);
#pragma unroll
    for (int ks = 0; ks < 2; ++ks) {
      const int a0 = __builtin_amdgcn_ds_bpermute(addrA,      c[2 * ks][0]);
      const int b0 = __builtin_amdgcn_ds_bpermute(addrA,      c[2 * ks + 1][0]);
      const int a1 = __builtin_amdgcn_ds_bpermute(addrA,      c[2 * ks][1]);
      const int b1 = __builtin_amdgcn_ds_bpermute(addrA,      c[2 * ks + 1][1]);
      const int a2 = __builtin_amdgcn_ds_bpermute(addrA + 64, c[2 * ks][0]);
      const int b2 = __builtin_amdgcn_ds_bpermute(addrA + 64, c[2 * ks + 1][0]);
      const int a3 = __builtin_amdgcn_ds_bpermute(addrA + 64, c[2 * ks][1]);
      const int b3 = __builtin_amdgcn_ds_bpermute(addrA + 64, c[2 * ks + 1][1]);
      i32x4v pw;
      pw[0] = hi_m ? b0 : a0;
      pw[1] = hi_m ? b1 : a1;
      pw[2] = hi_m ? b2 : a2;
      pw[3] = hi_m ? b3 : a3;
      const short8 pa = __builtin_bit_cast(short8, pw);
#pragma unroll
      for (int n = 0; n < 4; ++n) {
        const short8 vb = *(const short8*)((const char*)Vt[cur] + (n * 16 + lr) * 128 +
                              ((ks * 64 + lg * 16) ^ ((lr & 7) << 4)));
        oacc[n] = __builtin_amdgcn_mfma_f32_16x16x32_bf16(pa, vb, oacc[n], 0, 0, 0);
      }
    }
    __builtin_amdgcn_s_setprio(0);

    // ---- late V write into the other buffer ----
#pragma unroll
    for (int i = 0; i < 8; ++i)
      Vt[cur ^ 1][(w * 16 + i) * 64 + (l ^ ((i & 7) << 3))] = (unsigned short)nv0[i];
#pragma unroll
    for (int i = 8; i < 16; ++i)
      Vt[cur ^ 1][(w * 16 + i) * 64 + (l ^ ((i & 7) << 3))] = (unsigned short)nv1[i - 8];
    __syncthreads();
  }

  // ---- epilogue: store UNNORMALIZED partial + {m,l} ----
#pragma unroll
  for (int r = 0; r < 4; ++r) {
    const int row = q0 + w * 16 + lg * 4 + r;
    if (row >= S_) continue;
#pragma unroll
    for (int n = 0; n < 4; ++n)
      Opart[(size_t)row * DIM_ + h * 64 + n * 16 + lr] = f2b(oacc[n][r]);
  }
  if (l < 16) {                       // lg==0 lane holds (m,l) for q = lr
    const int row = q0 + w * 16 + lr;
    if (row < S_) {
      float2 v; v.x = m_run; v.y = l_run;
      *(float2*)(ml + ((size_t)(sv * S_ + row) * HEADS_ + h) * 2) = v;
    }
  }
}

// ============================================================================
// merge split-S partials (LSE combine) + conv-branch add -> bf16
// ============================================================================
__global__ void merge_k(const unsigned short* __restrict__ Op0,
                        const unsigned short* __restrict__ Op1,
                        const float* __restrict__ ml,
                        const unsigned short* __restrict__ y2b,
                        unsigned short* __restrict__ dst)
{
  const int i = blockIdx.x * 256 + threadIdx.x;     // over S_*DIM_/8
  if (i >= S_ * DIM_ / 8) return;
  const int e = i * 8;
  const int row = e / DIM_, col = e % DIM_;
  const int h = col >> 6;
  const float* p0 = ml + ((size_t)row * HEADS_ + h) * 2;
  const float* p1 = ml + ((size_t)(S_ + row) * HEADS_ + h) * 2;
  const float m0 = p0[0], l0 = p0[1], m1 = p1[0], l1 = p1[1];
  const float M = fmaxf(m0, m1);
  const float w0 = exp2f(m0 - M), w1 = exp2f(m1 - M);
  const float inv = 1.f / (w0 * l0 + w1 * l1);
  const short8 a = *(const short8*)(Op0 + e);
  const short8 b = *(const short8*)(Op1 + e);
  const bool cadd = row >= T_;
  const unsigned short* yp = y2b + (size_t)(row - T_) * DIM_ + col;
  short8 o;
#pragma unroll
  for (int j = 0; j < 8; ++j) {
    float v = (w0 * b2f((unsigned short)a[j]) + w1 * b2f((unsigned short)b[j])) * inv;
    if (cadd) v += b2f(yp[j]);
    o[j] = (short)f2b(v);
  }
  *(short8*)(dst + e) = o;
}

// ============================================================================
// fused input conversions (one launch)
// unit space: [0,U0) hidpad f4 | [U0,U1) wqkv f4 | then encb/w1p/w2p/bqkv scalar
// ============================================================================
#define U0_ 1228800
#define U1_ 3993600
#define U2_ 4427520
#define U3_ 5164800
#define U4_ 5902080
#define U5_ 5907840
__global__ void prep_all(const float* __restrict__ hid, const float* __restrict__ enc,
                         const float* __restrict__ w1, const float* __restrict__ w2,
                         const float* __restrict__ qw, const float* __restrict__ kw,
                         const float* __restrict__ vw, const float* __restrict__ qb2,
                         const float* __restrict__ kb2, const float* __restrict__ vb2,
                         unsigned short* __restrict__ hidpad, unsigned short* __restrict__ encb,
                         unsigned short* __restrict__ w1p, unsigned short* __restrict__ w2p,
                         unsigned short* __restrict__ wqkv, float* __restrict__ bqkv)
{
  const int i = blockIdx.x * 256 + threadIdx.x;
  if (i < U0_) {                                   // hidpad (zero-padded), x4
    const int e = i * 4;
    const int r = e / DIM_;
    ushort4v o = (ushort4v){0, 0, 0, 0};
    if (r >= 256 && r < 256 + SV_) {
      const float4 v = *(const float4*)(hid + e - 256 * DIM_);
      o[0] = f2b(v.x); o[1] = f2b(v.y); o[2] = f2b(v.z); o[3] = f2b(v.w);
    }
    *(ushort4v*)(hidpad + e) = o;
  } else if (i < U1_) {                            // fused QKV weights, x4
    const int e = (i - U0_) * 4;
    const int which = e / (DIM_ * DIM_);
    const int j = e - which * DIM_ * DIM_;
    const float* s = which == 0 ? qw : which == 1 ? kw : vw;
    const float4 v = *(const float4*)(s + j);
    ushort4v o = {f2b(v.x), f2b(v.y), f2b(v.z), f2b(v.w)};
    *(ushort4v*)(wqkv + e) = o;
  } else if (i < U2_) {                            // encoder bf16
    const int e = i - U1_;
    encb[e] = f2b(enc[e]);
  } else if (i < U3_) {                            // conv1 w permute
    const int e = i - U2_;
    const int oc = e / (DIM_ * 3), rem = e % (DIM_ * 3);
    const int ks = rem / DIM_, ic = rem % DIM_;
    w1p[e] = f2b(w1[(size_t)oc * DIM_ * 3 + ic * 3 + ks]);
  } else if (i < U4_) {                            // conv2 w permute
    const int e = i - U3_;
    const int oc = e / (RANK_ * 3), rem = e % (RANK_ * 3);
    const int ks = rem / RANK_, rc = rem % RANK_;
    w2p[e] = f2b(w2[(size_t)oc * RANK_ * 3 + rc * 3 + ks]);
  } else if (i < U5_) {                            // fused QKV bias (f32)
    const int e = i - U4_;
    const int which = e / DIM_, j = e % DIM_;
    bqkv[e] = which == 0 ? qb2[j] : which == 1 ? kb2[j] : vb2[j];
  }
}

__global__ void cvt_w(const float* __restrict__ src, unsigned short* __restrict__ dst, int n)
{
  int i = blockIdx.x * 256 + threadIdx.x;
  if (i < n) dst[i] = f2b(src[i]);
}

// sum 12 split-K partials of y1^T [128][2048], GELU, write padded [2560][128]
__global__ void gelupad_k(const float* __restrict__ y1T, unsigned short* __restrict__ dst)
{
  int i = blockIdx.x * 256 + threadIdx.x;
  if (i >= 2560 * RANK_) return;
  int r = i / RANK_, rc = i % RANK_;
  unsigned short o = 0;
  if (r >= 256 && r < 256 + SV_) {
    int s = r - 256;
    float x = 0.f;
#pragma unroll
    for (int z = 0; z < 12; ++z)
      x += y1T[(size_t)z * RANK_ * SV_ + (size_t)rc * SV_ + s];
    o = f2b(0.5f * x * (1.f + erff(x * 0.70710678118654752f)));
  }
  dst[i] = o;
}

// LN over HD=64 + RoPE, bf16 in place; Q branch scaled by log2(e)/8
__global__ __launch_bounds__(256) void qknorm_rope(
    unsigned short* __restrict__ Qbb, unsigned short* __restrict__ Kbb,
    const float* __restrict__ nq_w, const float* __restrict__ nq_b,
    const float* __restrict__ nk_w, const float* __restrict__ nk_b,
    const float* __restrict__ cosT, const float* __restrict__ sinT)
{
  const int w = threadIdx.x >> 6, lane = threadIdx.x & 63;
  const int idx = blockIdx.x * 4 + w;
  if (idx >= S_ * HEADS_) return;
  const int s = idx / HEADS_, h = idx % HEADS_;
  unsigned short* X = blockIdx.y ? Kbb : Qbb;
  const float* wt = blockIdx.y ? nk_w : nq_w;
  const float* bt = blockIdx.y ? nk_b : nq_b;
  const size_t off = (size_t)s * DIM_ + h * HD_ + lane;
  float x = b2f(X[off]);
  float m = x;
#pragma unroll
  for (int o = 32; o; o >>= 1) m += __shfl_xor(m, o);
  m *= (1.f / 64.f);
  float d = x - m;
  float v = d * d;
#pragma unroll
  for (int o = 32; o; o >>= 1) v += __shfl_xor(v, o);
  v *= (1.f / 64.f);
  float y = d * rsqrtf(v + 1e-6f) * wt[lane] + bt[lane];
  if (s >= T_) {
    float p = __shfl_xor(y, 1);
    float rot = (lane & 1) ? p : -p;
    int sv = s - T_;
    y = y * cosT[(size_t)sv * HD_ + lane] + rot * sinT[(size_t)sv * HD_ + lane];
  }
  if (!blockIdx.y) y *= 0.18033688011112042f;   // (1/8) * log2(e)
  X[off] = f2b(y);
}

// ============================================================================
extern "C" void kernel_launch(void* const* d_in, const int* in_sizes, int n_in,
                              void* d_out, int out_size, void* d_ws, size_t ws_size,
                              hipStream_t stream)
{
  const float* hidden  = (const float*)d_in[0];
  const float* encoder = (const float*)d_in[1];
  const float* cosT    = (const float*)d_in[2];
  const float* sinT    = (const float*)d_in[3];
  const float* to_q_w  = (const float*)d_in[4];
  const float* to_q_b  = (const float*)d_in[5];
  const float* to_k_w  = (const float*)d_in[6];
  const float* to_k_b  = (const float*)d_in[7];
  const float* to_v_w  = (const float*)d_in[8];
  const float* to_v_b  = (const float*)d_in[9];
  const float* nq_w    = (const float*)d_in[10];
  const float* nq_b    = (const float*)d_in[11];
  const float* nk_w    = (const float*)d_in[12];
  const float* nk_b    = (const float*)d_in[13];
  const float* conv1_w = (const float*)d_in[14];
  const float* conv2_w = (const float*)d_in[15];
  const float* to_out_w = (const float*)d_in[16];
  const float* to_out_b = (const float*)d_in[17];
  float* out = (float*)d_out;

  // ---- workspace layout: 83.09 MB total (>=85.58 MB proven available) ----
  char* p = (char*)d_ws;
  unsigned short* hidpad = (unsigned short*)p;  p += (size_t)2560 * DIM_ * 2;        // 9.83 MB (later Opart0)
  unsigned short* y2b    = (unsigned short*)p;  p += (size_t)SV_ * DIM_ * 2;         // 7.86 MB
  unsigned short* wqkv   = (unsigned short*)p;  p += (size_t)3 * DIM_ * DIM_ * 2;    // 22.12 MB
  unsigned short* w1p    = (unsigned short*)p;  p += (size_t)RANK_ * DIM_ * 3 * 2;   // 1.47 MB
  unsigned short* w2p    = (unsigned short*)p;  p += (size_t)DIM_ * RANK_ * 3 * 2;   // 1.47 MB
  unsigned short* QKVbb  = (unsigned short*)p;  p += (size_t)3 * S_ * DIM_ * 2;      // 26.20 MB
  unsigned short* encb   = (unsigned short*)p;  p += (size_t)T_ * DIM_ * 2;          // 0.87 MB
  float*          y1T    = (float*)p;           p += (size_t)12 * RANK_ * SV_ * 4;   // 12.58 MB (later Opart1+ml)
  unsigned short* gelup  = (unsigned short*)p;  p += (size_t)2560 * RANK_ * 2;       // 0.66 MB
  float*          bqkv   = (float*)p;           p += (size_t)3 * DIM_ * 4;           // 23 KB
  unsigned short* Qbb = QKVbb;
  unsigned short* Kbb = QKVbb + (size_t)S_ * DIM_;
  unsigned short* Vbb = QKVbb + (size_t)2 * S_ * DIM_;
  // split-S partial buffers overlay dead regions (hidpad, y1T)
  unsigned short* Op0 = hidpad;                          // 8.73 MB <= 9.83
  unsigned short* Op1 = (unsigned short*)y1T;            // 8.73 MB
  float*          ml  = (float*)((char*)y1T + (size_t)S_ * DIM_ * 2);  // 1.09 MB (fits)

  // ---- fused input conversions ----
  prep_all<<<(U5_ + 255) / 256, 256, 0, stream>>>(
      hidden, encoder, conv1_w, conv2_w, to_q_w, to_k_w, to_v_w,
      to_q_b, to_k_b, to_v_b, hidpad, encb, w1p, w2p, wqkv, bqkv);

  // ---- conv branch ----
  gemm_mfma<3, 0><<<dim3(SV_ / BN, 1, 12), 256, 0, stream>>>(
      w1p, nullptr, hidpad, nullptr, y1T, RANK_, SV_, 480, DIM_ * 3, DIM_, 1);
  gelupad_k<<<(2560 * RANK_ + 255) / 256, 256, 0, stream>>>(y1T, gelup);
  gemm_mfma<1, 1><<<dim3(DIM_ / BN, SV_ / BM), 256, 0, stream>>>(
      gelup, nullptr, w2p, nullptr, y2b, SV_, DIM_, RANK_ * 3, RANK_ * 3, RANK_ * 3, RANK_);

  // ---- fused QKV projection (bf16 out) ----
  const unsigned short* hid0 = hidpad + (size_t)256 * DIM_;
  gemm_mfma<2, 3><<<dim3(3 * DIM_ / BN, (S_ + BM - 1) / BM), 256, 0, stream>>>(
      encb, hid0, wqkv, bqkv, QKVbb, S_, 3 * DIM_, DIM_, DIM_, DIM_, 1);

  // ---- LN + RoPE (bf16 in place; Q scaled log2e/8) ----
  qknorm_rope<<<dim3((S_ * HEADS_ + 3) / 4, 2), 256, 0, stream>>>(
      Qbb, Kbb, nq_w, nq_b, nk_w, nk_b, cosT, sinT);

  // ---- MFMA flash attention, split-S x2 (partials + ml) ----
  attn_mfma<<<dim3((S_ + 63) / 64, HEADS_, 2), 256, 0, stream>>>(
      Qbb, Kbb, Vbb, Op0, Op1, ml);

  // ---- LSE merge + conv-branch add -> Qbb ----
  merge_k<<<(S_ * DIM_ / 8 + 255) / 256, 256, 0, stream>>>(Op0, Op1, ml, y2b, Qbb);

  // ---- output projection -> d_out (fp32, tuple remap) ----
  cvt_w<<<(DIM_ * DIM_ + 255) / 256, 256, 0, stream>>>(to_out_w, wqkv, DIM_ * DIM_);
  gemm_mfma<0, 2><<<dim3(DIM_ / BN, (S_ + BM - 1) / BM), 256, 0, stream>>>(
      Qbb, nullptr, wqkv, to_out_b, out, S_, DIM_, DIM_, DIM_, DIM_, 1);
}